// Round 1
// baseline (2027.554 us; speedup 1.0000x reference)
//
#include <hip/hip_runtime.h>
#include <math.h>

#define NN 100000
#define EE 400000
#define GG 4096
#define INF_ 27
#define CC 128   // H*D
#define HH 4
#define DD 32

// ---- ordered-uint encoding for float atomicMax ----
static __device__ __forceinline__ unsigned fenc(float x){
  unsigned u = __float_as_uint(x);
  return (u & 0x80000000u) ? ~u : (u | 0x80000000u);
}
static __device__ __forceinline__ float fdec(unsigned u){
  return (u & 0x80000000u) ? __uint_as_float(u & 0x7fffffffu) : __uint_as_float(~u);
}
#define ENC_NEG_INF 0x007fffffu   // fenc(-inf)

// ---- init scratch: per-node softmax stats, per-graph sum/max ----
__global__ void k_init(unsigned* __restrict__ menc, float* __restrict__ ssum,
                       float* __restrict__ sumg, unsigned* __restrict__ maxg){
  int i = blockIdx.x*blockDim.x + threadIdx.x;
  int st = gridDim.x*blockDim.x;
  for (int j=i; j<NN*HH; j+=st){ menc[j]=ENC_NEG_INF; ssum[j]=0.f; }
  if (sumg){
    for (int j=i; j<GG*DD; j+=st){ sumg[j]=0.f; maxg[j]=ENC_NEG_INF; }
  }
}

// ---- layer1: feat = x@fc1^T, acc = x@res1^T + bias1, el/er attn dots ----
__global__ __launch_bounds__(128) void k_feat1(
    const float* __restrict__ x, const float* __restrict__ fcw,
    const float* __restrict__ resw, const float* __restrict__ bias,
    const float* __restrict__ al, const float* __restrict__ ar,
    float* __restrict__ feat, float* __restrict__ acc,
    float* __restrict__ el, float* __restrict__ er)
{
  __shared__ float xs[INF_];
  __shared__ float w1[CC*INF_], w2[CC*INF_];
  const int t = threadIdx.x;
  for (int i=t; i<CC*INF_; i+=128){ w1[i]=fcw[i]; w2[i]=resw[i]; }
  const float alv = al[t], arv = ar[t], bv = bias[t];
  for (int n = blockIdx.x; n < NN; n += gridDim.x){
    __syncthreads();
    if (t < INF_) xs[t] = x[n*INF_ + t];
    __syncthreads();
    float vf = 0.f, vr = 0.f;
    #pragma unroll
    for (int k=0;k<INF_;k++){
      float xv = xs[k];
      vf = fmaf(xv, w1[t*INF_+k], vf);
      vr = fmaf(xv, w2[t*INF_+k], vr);
    }
    feat[n*CC+t] = vf;
    acc[n*CC+t]  = vr + bv;
    float la = vf*alv, ra = vf*arv;
    #pragma unroll
    for (int o=16;o;o>>=1){ la += __shfl_xor(la,o,32); ra += __shfl_xor(ra,o,32); }
    if ((t&31)==0){ el[n*HH+(t>>5)] = la; er[n*HH+(t>>5)] = ra; }
  }
}

// ---- layer2 GEMM: W held in VGPRs (pair-split dot); acc <- h + bias2 in place ----
__global__ __launch_bounds__(256) void k_feat2(
    const float* __restrict__ hbuf, const float* __restrict__ fcw,
    const float* __restrict__ bias2, const float* __restrict__ al, const float* __restrict__ ar,
    float* __restrict__ feat, float* __restrict__ acc,
    float* __restrict__ el, float* __restrict__ er)
{
  __shared__ float xs[CC];
  const int t = threadIdx.x;
  const int c = t >> 1;       // output channel 0..127
  const int half = t & 1;     // which half of the 128-dot
  const int wv = t >> 6;      // wave id == head id (wave w covers c=32w..32w+31)
  float4 wreg[16];
  const float4* fw4 = (const float4*)(fcw + c*CC + half*64);
  #pragma unroll
  for (int i=0;i<16;i++) wreg[i] = fw4[i];
  const float alv = al[c], arv = ar[c], bv = bias2[c];
  const float4* xs4 = (const float4*)xs;
  for (int n = blockIdx.x; n < NN; n += gridDim.x){
    __syncthreads();
    if (t < CC) xs[t] = hbuf[n*CC + t];
    __syncthreads();
    float vf = 0.f;
    #pragma unroll
    for (int i=0;i<16;i++){
      float4 xv = xs4[half*16 + i];
      vf = fmaf(xv.x, wreg[i].x, vf);
      vf = fmaf(xv.y, wreg[i].y, vf);
      vf = fmaf(xv.z, wreg[i].z, vf);
      vf = fmaf(xv.w, wreg[i].w, vf);
    }
    vf += __shfl_xor(vf, 1);   // both lanes of the pair now hold the full dot
    if (half == 0) feat[n*CC + c] = vf;
    else           acc[n*CC + c]  = xs[c] + bv;   // residual + bias (in-place safe)
    float la = half ? 0.f : vf*alv;
    float ra = half ? 0.f : vf*arv;
    #pragma unroll
    for (int o=32;o;o>>=1){ la += __shfl_xor(la,o); ra += __shfl_xor(ra,o); }
    if ((t&63)==0){ el[n*HH+wv] = la; er[n*HH+wv] = ra; }
  }
}

// ---- edge pass A: segment max of leaky_relu(el[src]+er[dst]) over dst ----
__global__ void k_edge_max(const int* __restrict__ src, const int* __restrict__ dst,
                           const float* __restrict__ el, const float* __restrict__ er,
                           unsigned* __restrict__ menc){
  int i = blockIdx.x*blockDim.x + threadIdx.x;
  if (i >= EE) return;
  int s0 = src[i], d0 = dst[i];
  #pragma unroll
  for (int h=0;h<HH;h++){
    float v = el[s0*HH+h] + er[d0*HH+h];
    v = v > 0.f ? v : 0.2f*v;
    atomicMax(&menc[d0*HH+h], fenc(v));
  }
}

// ---- edge pass B: segment sum of exp(e - m[dst]) ----
__global__ void k_edge_sum(const int* __restrict__ src, const int* __restrict__ dst,
                           const float* __restrict__ el, const float* __restrict__ er,
                           const unsigned* __restrict__ menc, float* __restrict__ ssum){
  int i = blockIdx.x*blockDim.x + threadIdx.x;
  if (i >= EE) return;
  int s0 = src[i], d0 = dst[i];
  #pragma unroll
  for (int h=0;h<HH;h++){
    float v = el[s0*HH+h] + er[d0*HH+h];
    v = v > 0.f ? v : 0.2f*v;
    float ex = expf(v - fdec(menc[d0*HH+h]));
    atomicAdd(&ssum[d0*HH+h], ex);
  }
}

// ---- edge pass C: acc[dst] += feat[src] * a   (32 lanes per edge, float4 feat) ----
__global__ void k_edge_aggr(const int* __restrict__ src, const int* __restrict__ dst,
                            const float* __restrict__ el, const float* __restrict__ er,
                            const unsigned* __restrict__ menc, const float* __restrict__ ssum,
                            const float* __restrict__ feat, float* __restrict__ acc){
  long long tid = (long long)blockIdx.x*blockDim.x + threadIdx.x;
  if (tid >= (long long)EE*32) return;
  int e = (int)(tid >> 5), lane = (int)(tid & 31);
  int s0 = src[e], d0 = dst[e];
  int h = lane >> 3;           // 8 lanes (4 channels each) per head
  float v = el[s0*HH+h] + er[d0*HH+h];
  v = v > 0.f ? v : 0.2f*v;
  float a = expf(v - fdec(menc[d0*HH+h])) / ssum[d0*HH+h];
  float4 f = ((const float4*)feat)[s0*32 + lane];
  float* p = acc + (size_t)d0*CC + lane*4;
  atomicAdd(p+0, f.x*a);
  atomicAdd(p+1, f.y*a);
  atomicAdd(p+2, f.z*a);
  atomicAdd(p+3, f.w*a);
}

// ---- layer1 epilogue: ELU in place ----
__global__ void k_elu(float* __restrict__ acc){
  int i = blockIdx.x*blockDim.x + threadIdx.x;
  int st = gridDim.x*blockDim.x;
  for (int j=i; j<NN*CC; j+=st){
    float v = acc[j];
    acc[j] = v > 0.f ? v : expm1f(v);
  }
}

// ---- fused readout: head-mean, sigmoid gate, per-graph segment sum/max ----
__global__ void k_readout(const float* __restrict__ acc, const int* __restrict__ gid,
                          const float* __restrict__ aww, const float* __restrict__ awb,
                          float* __restrict__ sumg, unsigned* __restrict__ maxg){
  int t = threadIdx.x;
  int n = blockIdx.x*8 + (t>>5);
  if (n >= NN) return;
  int lane = t & 31;
  const float* a = acc + (size_t)n*CC;
  float hm = 0.25f*(a[lane] + a[32+lane] + a[64+lane] + a[96+lane]);
  float p = hm * aww[lane];
  #pragma unroll
  for (int o=16;o;o>>=1) p += __shfl_xor(p,o,32);
  float w = 1.f/(1.f + expf(-(p + awb[0])));
  int g = gid[n];
  atomicAdd(&sumg[g*DD + lane], w*hm);
  atomicMax(&maxg[g*DD + lane], fenc(hm));
}

// ---- final: y = g@out_w^T + b, LayerNorm(128, no affine) ----
__global__ __launch_bounds__(128) void k_out(
    const float* __restrict__ sumg, const unsigned* __restrict__ maxg,
    const float* __restrict__ outw, const float* __restrict__ outb,
    float* __restrict__ out){
  __shared__ float gv[64];
  __shared__ float r1[2], r2[2];
  int g = blockIdx.x, t = threadIdx.x;
  if (t < 32) gv[t] = sumg[g*DD + t];
  else if (t < 64){
    float m = fdec(maxg[g*DD + (t-32)]);
    gv[t] = (m < -3.0e38f) ? 0.f : m;   // empty graph -> -inf -> 0
  }
  __syncthreads();
  float y = outb[t];
  #pragma unroll
  for (int j=0;j<64;j++) y = fmaf(gv[j], outw[t*64+j], y);
  float s1 = y, s2 = y*y;
  #pragma unroll
  for (int o=32;o;o>>=1){ s1 += __shfl_xor(s1,o); s2 += __shfl_xor(s2,o); }
  if ((t&63)==0){ r1[t>>6]=s1; r2[t>>6]=s2; }
  __syncthreads();
  float S1 = r1[0]+r1[1], S2 = r2[0]+r2[1];
  float mu = S1*(1.f/128.f);
  float var = S2*(1.f/128.f) - mu*mu;
  out[g*CC + t] = (y - mu) * rsqrtf(var + 1e-5f);
}

extern "C" void kernel_launch(void* const* d_in, const int* in_sizes, int n_in,
                              void* d_out, int out_size, void* d_ws, size_t ws_size,
                              hipStream_t stream){
  const float* x     = (const float*)d_in[0];
  const int*   src   = (const int*)d_in[1];
  const int*   dst   = (const int*)d_in[2];
  const int*   gid   = (const int*)d_in[3];
  const float* fc1w  = (const float*)d_in[4];
  const float* al1   = (const float*)d_in[5];
  const float* ar1   = (const float*)d_in[6];
  const float* res1w = (const float*)d_in[7];
  const float* b1    = (const float*)d_in[8];
  const float* fc2w  = (const float*)d_in[9];
  const float* al2   = (const float*)d_in[10];
  const float* ar2   = (const float*)d_in[11];
  const float* b2    = (const float*)d_in[12];
  const float* aww   = (const float*)d_in[13];
  const float* awb   = (const float*)d_in[14];
  const float* outw  = (const float*)d_in[15];
  const float* outb  = (const float*)d_in[16];
  float* out = (float*)d_out;

  float* feat = (float*)d_ws;                     // N*128
  float* acc  = feat + (size_t)NN*CC;             // N*128
  float* el   = acc  + (size_t)NN*CC;             // N*4
  float* er   = el + (size_t)NN*HH;               // N*4
  unsigned* menc = (unsigned*)(er + (size_t)NN*HH);  // N*4
  float* ssum = (float*)(menc + (size_t)NN*HH);   // N*4
  float* sumg = ssum + (size_t)NN*HH;             // G*32
  unsigned* maxg = (unsigned*)(sumg + (size_t)GG*DD); // G*32

  const int EB = (EE + 255)/256;

  // ---- layer 1 ----
  k_feat1<<<2048,128,0,stream>>>(x, fc1w, res1w, b1, al1, ar1, feat, acc, el, er);
  k_init<<<512,256,0,stream>>>(menc, ssum, sumg, maxg);
  k_edge_max<<<EB,256,0,stream>>>(src,dst,el,er,menc);
  k_edge_sum<<<EB,256,0,stream>>>(src,dst,el,er,menc,ssum);
  k_edge_aggr<<<(EE*32)/256,256,0,stream>>>(src,dst,el,er,menc,ssum,feat,acc);
  k_elu<<<2048,256,0,stream>>>(acc);
  // ---- layer 2 (acc doubles as h input; residual+bias written in place) ----
  k_feat2<<<1024,256,0,stream>>>(acc, fc2w, b2, al2, ar2, feat, acc, el, er);
  k_init<<<512,256,0,stream>>>(menc, ssum, nullptr, nullptr);
  k_edge_max<<<EB,256,0,stream>>>(src,dst,el,er,menc);
  k_edge_sum<<<EB,256,0,stream>>>(src,dst,el,er,menc,ssum);
  k_edge_aggr<<<(EE*32)/256,256,0,stream>>>(src,dst,el,er,menc,ssum,feat,acc);
  // ---- readout + output ----
  k_readout<<<(NN+7)/8,256,0,stream>>>(acc,gid,aww,awb,sumg,maxg);
  k_out<<<GG,128,0,stream>>>(sumg,maxg,outw,outb,out);
}

// Round 2
// 553.986 us; speedup vs baseline: 3.6599x; 3.6599x over previous
//
#include <hip/hip_runtime.h>
#include <math.h>

#define NN 100000
#define EE 400000
#define GG 4096
#define INF_ 27
#define CC 128   // H*D
#define HH 4
#define DD 32
#define NB 98    // ceil(NN/1024) scan blocks

// ---- ordered-uint encoding for float atomicMax ----
static __device__ __forceinline__ unsigned fenc(float x){
  unsigned u = __float_as_uint(x);
  return (u & 0x80000000u) ? ~u : (u | 0x80000000u);
}
static __device__ __forceinline__ float fdec(unsigned u){
  return (u & 0x80000000u) ? __uint_as_float(u & 0x7fffffffu) : __uint_as_float(~u);
}
#define ENC_NEG_INF 0x007fffffu   // fenc(-inf)

// ---- init: zero degree counts, init per-graph sum/max ----
__global__ void k_init0(int* __restrict__ deg, float* __restrict__ sumg,
                        unsigned* __restrict__ maxg){
  int i = blockIdx.x*blockDim.x + threadIdx.x;
  int st = gridDim.x*blockDim.x;
  for (int j=i; j<NN; j+=st) deg[j]=0;
  for (int j=i; j<GG*DD; j+=st){ sumg[j]=0.f; maxg[j]=ENC_NEG_INF; }
}

__global__ void k_count(const int* __restrict__ dst, int* __restrict__ deg){
  int i = blockIdx.x*blockDim.x + threadIdx.x;
  if (i < EE) atomicAdd(&deg[dst[i]], 1);
}

// ---- exclusive scan of deg -> rowptr (1024 elems/block) ----
__global__ __launch_bounds__(256) void k_scan_local(const int* __restrict__ deg,
                                                    int* __restrict__ rowptr,
                                                    int* __restrict__ bsum){
  __shared__ int sh[256];
  int t = threadIdx.x;
  int idx = blockIdx.x*1024 + t*4;
  int v0 = (idx+0<NN)?deg[idx+0]:0;
  int v1 = (idx+1<NN)?deg[idx+1]:0;
  int v2 = (idx+2<NN)?deg[idx+2]:0;
  int v3 = (idx+3<NN)?deg[idx+3]:0;
  sh[t] = v0+v1+v2+v3;
  __syncthreads();
  for (int o=1;o<256;o<<=1){
    int x = (t>=o)? sh[t-o] : 0;
    __syncthreads();
    sh[t] += x;
    __syncthreads();
  }
  int run = (t==0)? 0 : sh[t-1];
  if (t==255) bsum[blockIdx.x] = sh[255];
  if (idx+0<NN){ rowptr[idx+0]=run; run+=v0; }
  if (idx+1<NN){ rowptr[idx+1]=run; run+=v1; }
  if (idx+2<NN){ rowptr[idx+2]=run; run+=v2; }
  if (idx+3<NN){ rowptr[idx+3]=run; }
}

__global__ void k_scan_bsums(int* __restrict__ bsum, int* __restrict__ rowptr){
  if (threadIdx.x==0 && blockIdx.x==0){
    int run = 0;
    for (int b=0;b<NB;b++){ int v=bsum[b]; bsum[b]=run; run+=v; }
    rowptr[NN] = run;   // == EE
  }
}

__global__ __launch_bounds__(256) void k_scan_add(int* __restrict__ rowptr,
                                                  const int* __restrict__ bsum,
                                                  int* __restrict__ cursor){
  int idx = blockIdx.x*1024 + threadIdx.x*4;
  int off = bsum[blockIdx.x];
  #pragma unroll
  for (int i=0;i<4;i++){
    if (idx+i<NN){ int r = rowptr[idx+i]+off; rowptr[idx+i]=r; cursor[idx+i]=r; }
  }
}

__global__ void k_scatter(const int* __restrict__ src, const int* __restrict__ dst,
                          int* __restrict__ cursor, int* __restrict__ csr_src){
  int i = blockIdx.x*blockDim.x + threadIdx.x;
  if (i < EE){
    int pos = atomicAdd(&cursor[dst[i]], 1);
    csr_src[pos] = src[i];
  }
}

// ---- layer1: feat = x@fc1^T, acc = x@res1^T + bias1, el/er attn dots ----
__global__ __launch_bounds__(128) void k_feat1(
    const float* __restrict__ x, const float* __restrict__ fcw,
    const float* __restrict__ resw, const float* __restrict__ bias,
    const float* __restrict__ al, const float* __restrict__ ar,
    float* __restrict__ feat, float* __restrict__ acc,
    float* __restrict__ el, float* __restrict__ er)
{
  __shared__ float xs[INF_];
  __shared__ float w1[CC*INF_], w2[CC*INF_];
  const int t = threadIdx.x;
  for (int i=t; i<CC*INF_; i+=128){ w1[i]=fcw[i]; w2[i]=resw[i]; }
  const float alv = al[t], arv = ar[t], bv = bias[t];
  for (int n = blockIdx.x; n < NN; n += gridDim.x){
    __syncthreads();
    if (t < INF_) xs[t] = x[n*INF_ + t];
    __syncthreads();
    float vf = 0.f, vr = 0.f;
    #pragma unroll
    for (int k=0;k<INF_;k++){
      float xv = xs[k];
      vf = fmaf(xv, w1[t*INF_+k], vf);
      vr = fmaf(xv, w2[t*INF_+k], vr);
    }
    feat[n*CC+t] = vf;
    acc[n*CC+t]  = vr + bv;
    float la = vf*alv, ra = vf*arv;
    #pragma unroll
    for (int o=16;o;o>>=1){ la += __shfl_xor(la,o,32); ra += __shfl_xor(ra,o,32); }
    if ((t&31)==0){ el[n*HH+(t>>5)] = la; er[n*HH+(t>>5)] = ra; }
  }
}

// ---- layer2 GEMM: W in VGPRs (pair-split dot); ELU applied on load;
//      acc <- elu(h) + bias2 (identity residual) ----
__global__ __launch_bounds__(256) void k_feat2(
    const float* __restrict__ hbuf, const float* __restrict__ fcw,
    const float* __restrict__ bias2, const float* __restrict__ al, const float* __restrict__ ar,
    float* __restrict__ feat, float* __restrict__ acc,
    float* __restrict__ el, float* __restrict__ er)
{
  __shared__ float xs[CC];
  const int t = threadIdx.x;
  const int c = t >> 1;       // output channel 0..127
  const int half = t & 1;
  const int wv = t >> 6;      // wave id == head id
  float4 wreg[16];
  const float4* fw4 = (const float4*)(fcw + c*CC + half*64);
  #pragma unroll
  for (int i=0;i<16;i++) wreg[i] = fw4[i];
  const float alv = al[c], arv = ar[c], bv = bias2[c];
  const float4* xs4 = (const float4*)xs;
  for (int n = blockIdx.x; n < NN; n += gridDim.x){
    __syncthreads();
    if (t < CC){
      float v = hbuf[n*CC + t];
      xs[t] = v > 0.f ? v : expm1f(v);   // ELU fused on load
    }
    __syncthreads();
    float vf = 0.f;
    #pragma unroll
    for (int i=0;i<16;i++){
      float4 xv = xs4[half*16 + i];
      vf = fmaf(xv.x, wreg[i].x, vf);
      vf = fmaf(xv.y, wreg[i].y, vf);
      vf = fmaf(xv.z, wreg[i].z, vf);
      vf = fmaf(xv.w, wreg[i].w, vf);
    }
    vf += __shfl_xor(vf, 1);
    if (half == 0) feat[n*CC + c] = vf;
    else           acc[n*CC + c]  = xs[c] + bv;   // elu(h) + bias
    float la = half ? 0.f : vf*alv;
    float ra = half ? 0.f : vf*arv;
    #pragma unroll
    for (int o=32;o;o>>=1){ la += __shfl_xor(la,o); ra += __shfl_xor(ra,o); }
    if ((t&63)==0){ el[n*HH+wv] = la; er[n*HH+wv] = ra; }
  }
}

// ---- CSR-based per-node softmax + aggregation: NO atomics ----
// half-wave (32 lanes) per dst node; lane owns 4 channels (float4)
__global__ __launch_bounds__(256) void k_node_aggr(
    const int* __restrict__ rowptr, const int* __restrict__ csr_src,
    const float* __restrict__ el, const float* __restrict__ er,
    const float* __restrict__ feat, float* __restrict__ acc)
{
  int t = threadIdx.x;
  int n = blockIdx.x*8 + (t>>5);
  if (n >= NN) return;
  int lane = t & 31;
  int h = lane >> 3;
  int e0 = rowptr[n], e1 = rowptr[n+1];
  if (e0 == e1) return;
  float ern = er[n*HH + h];
  // pass 1: max
  float m = -3.4e38f;
  for (int j=e0;j<e1;j++){
    int s = csr_src[j];
    float v = el[s*HH+h] + ern;
    v = v > 0.f ? v : 0.2f*v;
    m = fmaxf(m, v);
  }
  // pass 2: sum of exp
  float ssum = 0.f;
  for (int j=e0;j<e1;j++){
    int s = csr_src[j];
    float v = el[s*HH+h] + ern;
    v = v > 0.f ? v : 0.2f*v;
    ssum += expf(v - m);
  }
  float inv = 1.f/ssum;
  // pass 3: aggregate
  float4 r = make_float4(0.f,0.f,0.f,0.f);
  for (int j=e0;j<e1;j++){
    int s = csr_src[j];
    float v = el[s*HH+h] + ern;
    v = v > 0.f ? v : 0.2f*v;
    float a = expf(v - m) * inv;
    float4 f = ((const float4*)feat)[s*32 + lane];
    r.x = fmaf(f.x, a, r.x);
    r.y = fmaf(f.y, a, r.y);
    r.z = fmaf(f.z, a, r.z);
    r.w = fmaf(f.w, a, r.w);
  }
  float4* p = (float4*)(acc + (size_t)n*CC + lane*4);
  float4 cur = *p;
  cur.x += r.x; cur.y += r.y; cur.z += r.z; cur.w += r.w;
  *p = cur;
}

// ---- fused readout: head-mean, sigmoid gate, per-graph segment sum/max ----
__global__ void k_readout(const float* __restrict__ acc, const int* __restrict__ gid,
                          const float* __restrict__ aww, const float* __restrict__ awb,
                          float* __restrict__ sumg, unsigned* __restrict__ maxg){
  int t = threadIdx.x;
  int n = blockIdx.x*8 + (t>>5);
  if (n >= NN) return;
  int lane = t & 31;
  const float* a = acc + (size_t)n*CC;
  float hm = 0.25f*(a[lane] + a[32+lane] + a[64+lane] + a[96+lane]);
  float p = hm * aww[lane];
  #pragma unroll
  for (int o=16;o;o>>=1) p += __shfl_xor(p,o,32);
  float w = 1.f/(1.f + expf(-(p + awb[0])));
  int g = gid[n];
  atomicAdd(&sumg[g*DD + lane], w*hm);
  atomicMax(&maxg[g*DD + lane], fenc(hm));
}

// ---- final: y = g@out_w^T + b, LayerNorm(128, no affine) ----
__global__ __launch_bounds__(128) void k_out(
    const float* __restrict__ sumg, const unsigned* __restrict__ maxg,
    const float* __restrict__ outw, const float* __restrict__ outb,
    float* __restrict__ out){
  __shared__ float gv[64];
  __shared__ float r1[2], r2[2];
  int g = blockIdx.x, t = threadIdx.x;
  if (t < 32) gv[t] = sumg[g*DD + t];
  else if (t < 64){
    float m = fdec(maxg[g*DD + (t-32)]);
    gv[t] = (m < -3.0e38f) ? 0.f : m;
  }
  __syncthreads();
  float y = outb[t];
  #pragma unroll
  for (int j=0;j<64;j++) y = fmaf(gv[j], outw[t*64+j], y);
  float s1 = y, s2 = y*y;
  #pragma unroll
  for (int o=32;o;o>>=1){ s1 += __shfl_xor(s1,o); s2 += __shfl_xor(s2,o); }
  if ((t&63)==0){ r1[t>>6]=s1; r2[t>>6]=s2; }
  __syncthreads();
  float S1 = r1[0]+r1[1], S2 = r2[0]+r2[1];
  float mu = S1*(1.f/128.f);
  float var = S2*(1.f/128.f) - mu*mu;
  out[g*CC + t] = (y - mu) * rsqrtf(var + 1e-5f);
}

extern "C" void kernel_launch(void* const* d_in, const int* in_sizes, int n_in,
                              void* d_out, int out_size, void* d_ws, size_t ws_size,
                              hipStream_t stream){
  const float* x     = (const float*)d_in[0];
  const int*   src   = (const int*)d_in[1];
  const int*   dst   = (const int*)d_in[2];
  const int*   gid   = (const int*)d_in[3];
  const float* fc1w  = (const float*)d_in[4];
  const float* al1   = (const float*)d_in[5];
  const float* ar1   = (const float*)d_in[6];
  const float* res1w = (const float*)d_in[7];
  const float* b1    = (const float*)d_in[8];
  const float* fc2w  = (const float*)d_in[9];
  const float* al2   = (const float*)d_in[10];
  const float* ar2   = (const float*)d_in[11];
  const float* b2    = (const float*)d_in[12];
  const float* aww   = (const float*)d_in[13];
  const float* awb   = (const float*)d_in[14];
  const float* outw  = (const float*)d_in[15];
  const float* outb  = (const float*)d_in[16];
  float* out = (float*)d_out;

  float* feat = (float*)d_ws;                       // N*128
  float* acc  = feat + (size_t)NN*CC;               // N*128
  float* el   = acc  + (size_t)NN*CC;               // N*4
  float* er   = el + (size_t)NN*HH;                 // N*4
  float* sumg = er + (size_t)NN*HH;                 // G*32
  unsigned* maxg = (unsigned*)(sumg + (size_t)GG*DD); // G*32
  int* deg    = (int*)(maxg + (size_t)GG*DD);       // N
  int* rowptr = deg + NN;                           // N+1
  int* cursor = rowptr + NN + 1;                    // N
  int* bsum   = cursor + NN;                        // 128 (NB=98)
  int* csr_src= bsum + 128;                         // E

  const int EB = (EE + 255)/256;

  // ---- CSR build (once; shared by both layers) ----
  k_init0<<<512,256,0,stream>>>(deg, sumg, maxg);
  k_count<<<EB,256,0,stream>>>(dst, deg);
  k_scan_local<<<NB,256,0,stream>>>(deg, rowptr, bsum);
  k_scan_bsums<<<1,64,0,stream>>>(bsum, rowptr);
  k_scan_add<<<NB,256,0,stream>>>(rowptr, bsum, cursor);
  k_scatter<<<EB,256,0,stream>>>(src, dst, cursor, csr_src);

  // ---- layer 1 ----
  k_feat1<<<2048,128,0,stream>>>(x, fc1w, res1w, b1, al1, ar1, feat, acc, el, er);
  k_node_aggr<<<(NN+7)/8,256,0,stream>>>(rowptr, csr_src, el, er, feat, acc);
  // ---- layer 2 (ELU fused into feat2 load; residual+bias written in place) ----
  k_feat2<<<1024,256,0,stream>>>(acc, fc2w, b2, al2, ar2, feat, acc, el, er);
  k_node_aggr<<<(NN+7)/8,256,0,stream>>>(rowptr, csr_src, el, er, feat, acc);
  // ---- readout + output ----
  k_readout<<<(NN+7)/8,256,0,stream>>>(acc,gid,aww,awb,sumg,maxg);
  k_out<<<GG,128,0,stream>>>(sumg,maxg,outw,outb,out);
}

// Round 3
// 365.468 us; speedup vs baseline: 5.5478x; 1.5158x over previous
//
#include <hip/hip_runtime.h>
#include <math.h>

#define NN 100000
#define EE 400000
#define GG 4096
#define INF_ 27
#define CC 128   // H*D
#define HH 4
#define DD 32
#define NB 98    // ceil(NN/1024) scan blocks

typedef short bf16x8 __attribute__((ext_vector_type(8)));
typedef float f32x4 __attribute__((ext_vector_type(4)));

// ---- bf16 helpers (RNE) ----
static __device__ __forceinline__ unsigned short f2bf(float f){
  unsigned u = __float_as_uint(f);
  u += 0x7fffu + ((u>>16)&1u);
  return (unsigned short)(u>>16);
}
static __device__ __forceinline__ float bf2f(unsigned short s){
  return __uint_as_float(((unsigned)s)<<16);
}

// ---- ordered-uint encoding for float atomicMax ----
static __device__ __forceinline__ unsigned fenc(float x){
  unsigned u = __float_as_uint(x);
  return (u & 0x80000000u) ? ~u : (u | 0x80000000u);
}
static __device__ __forceinline__ float fdec(unsigned u){
  return (u & 0x80000000u) ? __uint_as_float(u & 0x7fffffffu) : __uint_as_float(~u);
}
#define ENC_NEG_INF 0x007fffffu

// ---- init: zero degree counts, init per-graph sum/max ----
__global__ void k_init0(int* __restrict__ deg, float* __restrict__ sumg,
                        unsigned* __restrict__ maxg){
  int i = blockIdx.x*blockDim.x + threadIdx.x;
  int st = gridDim.x*blockDim.x;
  for (int j=i; j<NN; j+=st) deg[j]=0;
  for (int j=i; j<GG*DD; j+=st){ sumg[j]=0.f; maxg[j]=ENC_NEG_INF; }
}

__global__ void k_count(const int* __restrict__ dst, int* __restrict__ deg){
  int i = blockIdx.x*blockDim.x + threadIdx.x;
  if (i < EE) atomicAdd(&deg[dst[i]], 1);
}

__global__ __launch_bounds__(256) void k_scan_local(const int* __restrict__ deg,
                                                    int* __restrict__ rowptr,
                                                    int* __restrict__ bsum){
  __shared__ int sh[256];
  int t = threadIdx.x;
  int idx = blockIdx.x*1024 + t*4;
  int v0 = (idx+0<NN)?deg[idx+0]:0;
  int v1 = (idx+1<NN)?deg[idx+1]:0;
  int v2 = (idx+2<NN)?deg[idx+2]:0;
  int v3 = (idx+3<NN)?deg[idx+3]:0;
  sh[t] = v0+v1+v2+v3;
  __syncthreads();
  for (int o=1;o<256;o<<=1){
    int x = (t>=o)? sh[t-o] : 0;
    __syncthreads();
    sh[t] += x;
    __syncthreads();
  }
  int run = (t==0)? 0 : sh[t-1];
  if (t==255) bsum[blockIdx.x] = sh[255];
  if (idx+0<NN){ rowptr[idx+0]=run; run+=v0; }
  if (idx+1<NN){ rowptr[idx+1]=run; run+=v1; }
  if (idx+2<NN){ rowptr[idx+2]=run; run+=v2; }
  if (idx+3<NN){ rowptr[idx+3]=run; }
}

__global__ void k_scan_bsums(int* __restrict__ bsum, int* __restrict__ rowptr){
  if (threadIdx.x==0 && blockIdx.x==0){
    int run = 0;
    for (int b=0;b<NB;b++){ int v=bsum[b]; bsum[b]=run; run+=v; }
    rowptr[NN] = run;
  }
}

__global__ __launch_bounds__(256) void k_scan_add(int* __restrict__ rowptr,
                                                  const int* __restrict__ bsum,
                                                  int* __restrict__ cursor){
  int idx = blockIdx.x*1024 + threadIdx.x*4;
  int off = bsum[blockIdx.x];
  #pragma unroll
  for (int i=0;i<4;i++){
    if (idx+i<NN){ int r = rowptr[idx+i]+off; rowptr[idx+i]=r; cursor[idx+i]=r; }
  }
}

__global__ void k_scatter(const int* __restrict__ src, const int* __restrict__ dst,
                          int* __restrict__ cursor, int* __restrict__ csr_src){
  int i = blockIdx.x*blockDim.x + threadIdx.x;
  if (i < EE){
    int pos = atomicAdd(&cursor[dst[i]], 1);
    csr_src[pos] = src[i];
  }
}

// ---- fc2 weights -> bf16 ----
__global__ void k_cvtw2(const float* __restrict__ w, unsigned short* __restrict__ wb){
  int i = blockIdx.x*256 + threadIdx.x;
  if (i < CC*CC) wb[i] = f2bf(w[i]);
}

// ---- layer1: feat(bf16) = x@fc1^T, acc = x@res1^T + bias1, el/er; W in VGPRs ----
__global__ __launch_bounds__(128) void k_feat1(
    const float* __restrict__ x, const float* __restrict__ fcw,
    const float* __restrict__ resw, const float* __restrict__ bias,
    const float* __restrict__ al, const float* __restrict__ ar,
    unsigned short* __restrict__ featb, float* __restrict__ acc,
    float* __restrict__ el, float* __restrict__ er)
{
  __shared__ float xs[8*INF_];
  const int t = threadIdx.x;
  float w1r[INF_], w2r[INF_];
  #pragma unroll
  for (int k=0;k<INF_;k++){ w1r[k]=fcw[t*INF_+k]; w2r[k]=resw[t*INF_+k]; }
  const float alv = al[t], arv = ar[t], bv = bias[t];
  for (int base = blockIdx.x*8; base < NN; base += gridDim.x*8){
    __syncthreads();
    int nb = min(8, NN-base);
    int cnt = nb*INF_;
    for (int i=t;i<cnt;i+=128) xs[i] = x[base*INF_ + i];
    __syncthreads();
    for (int i=0;i<nb;i++){
      int n = base+i;
      float vf=0.f, vr=0.f;
      #pragma unroll
      for (int k=0;k<INF_;k++){
        float xv = xs[i*INF_+k];
        vf = fmaf(xv, w1r[k], vf);
        vr = fmaf(xv, w2r[k], vr);
      }
      featb[(size_t)n*CC+t] = f2bf(vf);
      acc[(size_t)n*CC+t]  = vr + bv;
      float la = vf*alv, ra = vf*arv;
      #pragma unroll
      for (int o=16;o;o>>=1){ la += __shfl_xor(la,o,32); ra += __shfl_xor(ra,o,32); }
      if ((t&31)==0){ el[n*HH+(t>>5)] = la; er[n*HH+(t>>5)] = ra; }
    }
  }
}

// ---- layer2 GEMM via MFMA: featb2 = bf16(hb @ fc2^T), el/er dots ----
// wave = 16-node tile x 64-col half; W frags hoisted in VGPRs
__global__ __launch_bounds__(256) void k_feat2(
    const unsigned short* __restrict__ hb, const unsigned short* __restrict__ wb2,
    const float* __restrict__ al, const float* __restrict__ ar,
    unsigned short* __restrict__ featb, float* __restrict__ el, float* __restrict__ er)
{
  int wid = (blockIdx.x*256 + threadIdx.x) >> 6;
  int lane = threadIdx.x & 63;
  int tile = wid >> 1;
  int ch = wid & 1;
  if (tile >= NN/16) return;
  int l15 = lane & 15, khi = lane >> 4;
  int n0 = tile*16;
  bf16x8 wf[4][4];
  #pragma unroll
  for (int ct=0; ct<4; ct++)
    #pragma unroll
    for (int ks=0; ks<4; ks++)
      wf[ct][ks] = *(const bf16x8*)(wb2 + (size_t)(ch*64+ct*16+l15)*CC + ks*32 + khi*8);
  bf16x8 af[4];
  #pragma unroll
  for (int ks=0; ks<4; ks++)
    af[ks] = *(const bf16x8*)(hb + (size_t)(n0+l15)*CC + ks*32 + khi*8);
  f32x4 accf[4] = {{0.f,0.f,0.f,0.f},{0.f,0.f,0.f,0.f},{0.f,0.f,0.f,0.f},{0.f,0.f,0.f,0.f}};
  #pragma unroll
  for (int ks=0; ks<4; ks++)
    #pragma unroll
    for (int ct=0; ct<4; ct++)
      accf[ct] = __builtin_amdgcn_mfma_f32_16x16x32_bf16(af[ks], wf[ct][ks], accf[ct], 0,0,0);
  #pragma unroll
  for (int ct=0; ct<4; ct++)
    #pragma unroll
    for (int r=0;r<4;r++)
      featb[(size_t)(n0+khi*4+r)*CC + ch*64+ct*16+l15] = f2bf(accf[ct][r]);
  #pragma unroll
  for (int hh=0; hh<2; hh++){
    int c0 = ch*64 + hh*32 + l15;
    float a0 = al[c0], a1 = al[c0+16], b0 = ar[c0], b1 = ar[c0+16];
    #pragma unroll
    for (int r=0;r<4;r++){
      float pe = accf[2*hh][r]*a0 + accf[2*hh+1][r]*a1;
      float pr = accf[2*hh][r]*b0 + accf[2*hh+1][r]*b1;
      #pragma unroll
      for (int o=8;o;o>>=1){ pe += __shfl_xor(pe,o,16); pr += __shfl_xor(pr,o,16); }
      if (l15==0){
        int n = n0 + khi*4 + r;
        el[n*HH + ch*2+hh] = pe;
        er[n*HH + ch*2+hh] = pr;
      }
    }
  }
}

// ---- layer1 aggregation + fused ELU + bias2 prep (no atomics) ----
// half-wave per dst node; lane owns 4 channels
__global__ __launch_bounds__(256) void k_aggr1(
    const int* __restrict__ rowptr, const int* __restrict__ csr_src,
    const float* __restrict__ el, const float* __restrict__ er,
    const unsigned short* __restrict__ featb, float* __restrict__ acc,
    const float* __restrict__ b2, unsigned short* __restrict__ hb)
{
  int t = threadIdx.x;
  int n = blockIdx.x*8 + (t>>5);
  if (n >= NN) return;
  int lane = t & 31;
  int h = lane >> 3;
  int e0 = rowptr[n], e1 = rowptr[n+1];
  float ern = er[n*HH + h];
  float m = -3.4e38f;
  for (int j=e0;j<e1;j++){
    int s = csr_src[j];
    float v = el[s*HH+h] + ern;
    v = v > 0.f ? v : 0.2f*v;
    m = fmaxf(m, v);
  }
  float ssum = 0.f;
  for (int j=e0;j<e1;j++){
    int s = csr_src[j];
    float v = el[s*HH+h] + ern;
    v = v > 0.f ? v : 0.2f*v;
    ssum += expf(v - m);
  }
  float inv = (e1 > e0) ? 1.f/ssum : 0.f;
  float r0=0.f,r1=0.f,r2=0.f,r3=0.f;
  for (int j=e0;j<e1;j++){
    int s = csr_src[j];
    float v = el[s*HH+h] + ern;
    v = v > 0.f ? v : 0.2f*v;
    float a = expf(v - m) * inv;
    ushort4 f = *(const ushort4*)(featb + (size_t)s*CC + lane*4);
    r0 = fmaf(bf2f(f.x), a, r0);
    r1 = fmaf(bf2f(f.y), a, r1);
    r2 = fmaf(bf2f(f.z), a, r2);
    r3 = fmaf(bf2f(f.w), a, r3);
  }
  float4 ai = *(const float4*)(acc + (size_t)n*CC + lane*4);
  float e0v = ai.x + r0, e1v = ai.y + r1, e2v = ai.z + r2, e3v = ai.w + r3;
  e0v = e0v > 0.f ? e0v : expm1f(e0v);
  e1v = e1v > 0.f ? e1v : expm1f(e1v);
  e2v = e2v > 0.f ? e2v : expm1f(e2v);
  e3v = e3v > 0.f ? e3v : expm1f(e3v);
  ushort4 hb4; hb4.x=f2bf(e0v); hb4.y=f2bf(e1v); hb4.z=f2bf(e2v); hb4.w=f2bf(e3v);
  *(ushort4*)(hb + (size_t)n*CC + lane*4) = hb4;
  float4 bv = *(const float4*)(b2 + lane*4);
  float4 o; o.x=e0v+bv.x; o.y=e1v+bv.y; o.z=e2v+bv.z; o.w=e3v+bv.w;
  *(float4*)(acc + (size_t)n*CC + lane*4) = o;
}

// ---- layer2 aggregation + fused readout (head-mean, gate, graph atomics) ----
__global__ __launch_bounds__(256) void k_aggr2(
    const int* __restrict__ rowptr, const int* __restrict__ csr_src,
    const float* __restrict__ el, const float* __restrict__ er,
    const unsigned short* __restrict__ featb, const float* __restrict__ acc,
    const int* __restrict__ gid, const float* __restrict__ aww,
    const float* __restrict__ awb,
    float* __restrict__ sumg, unsigned* __restrict__ maxg)
{
  int t = threadIdx.x;
  int n = blockIdx.x*8 + (t>>5);
  if (n >= NN) return;
  int lane = t & 31;
  int h = lane >> 3;
  int e0 = rowptr[n], e1 = rowptr[n+1];
  float ern = er[n*HH + h];
  float m = -3.4e38f;
  for (int j=e0;j<e1;j++){
    int s = csr_src[j];
    float v = el[s*HH+h] + ern;
    v = v > 0.f ? v : 0.2f*v;
    m = fmaxf(m, v);
  }
  float ssum = 0.f;
  for (int j=e0;j<e1;j++){
    int s = csr_src[j];
    float v = el[s*HH+h] + ern;
    v = v > 0.f ? v : 0.2f*v;
    ssum += expf(v - m);
  }
  float inv = (e1 > e0) ? 1.f/ssum : 0.f;
  float r0=0.f,r1=0.f,r2=0.f,r3=0.f;
  for (int j=e0;j<e1;j++){
    int s = csr_src[j];
    float v = el[s*HH+h] + ern;
    v = v > 0.f ? v : 0.2f*v;
    float a = expf(v - m) * inv;
    ushort4 f = *(const ushort4*)(featb + (size_t)s*CC + lane*4);
    r0 = fmaf(bf2f(f.x), a, r0);
    r1 = fmaf(bf2f(f.y), a, r1);
    r2 = fmaf(bf2f(f.z), a, r2);
    r3 = fmaf(bf2f(f.w), a, r3);
  }
  float4 ai = *(const float4*)(acc + (size_t)n*CC + lane*4);
  float t0 = ai.x + r0, t1 = ai.y + r1, t2 = ai.z + r2, t3 = ai.w + r3;
  // head-mean across lanes (xor 8, 16 within the 32-lane group)
  float s0=t0,s1=t1,s2=t2,s3=t3;
  s0 += __shfl_xor(s0,8,32); s1 += __shfl_xor(s1,8,32);
  s2 += __shfl_xor(s2,8,32); s3 += __shfl_xor(s3,8,32);
  s0 += __shfl_xor(s0,16,32); s1 += __shfl_xor(s1,16,32);
  s2 += __shfl_xor(s2,16,32); s3 += __shfl_xor(s3,16,32);
  float hm0=0.25f*s0, hm1=0.25f*s1, hm2=0.25f*s2, hm3=0.25f*s3;
  float4 aw4 = *(const float4*)(aww + (lane&7)*4);
  float p = hm0*aw4.x + hm1*aw4.y + hm2*aw4.z + hm3*aw4.w;
  p += __shfl_xor(p,1,32); p += __shfl_xor(p,2,32); p += __shfl_xor(p,4,32);
  float w = 1.f/(1.f + expf(-(p + awb[0])));
  int g = gid[n];
  if (lane < 8){
    int b = g*DD + lane*4;
    atomicAdd(&sumg[b+0], w*hm0);
    atomicAdd(&sumg[b+1], w*hm1);
    atomicAdd(&sumg[b+2], w*hm2);
    atomicAdd(&sumg[b+3], w*hm3);
    atomicMax(&maxg[b+0], fenc(hm0));
    atomicMax(&maxg[b+1], fenc(hm1));
    atomicMax(&maxg[b+2], fenc(hm2));
    atomicMax(&maxg[b+3], fenc(hm3));
  }
}

// ---- final: y = g@out_w^T + b, LayerNorm(128, no affine) ----
__global__ __launch_bounds__(128) void k_out(
    const float* __restrict__ sumg, const unsigned* __restrict__ maxg,
    const float* __restrict__ outw, const float* __restrict__ outb,
    float* __restrict__ out){
  __shared__ float gv[64];
  __shared__ float r1[2], r2[2];
  int g = blockIdx.x, t = threadIdx.x;
  if (t < 32) gv[t] = sumg[g*DD + t];
  else if (t < 64){
    float m = fdec(maxg[g*DD + (t-32)]);
    gv[t] = (m < -3.0e38f) ? 0.f : m;
  }
  __syncthreads();
  float y = outb[t];
  #pragma unroll
  for (int j=0;j<64;j++) y = fmaf(gv[j], outw[t*64+j], y);
  float s1 = y, s2 = y*y;
  #pragma unroll
  for (int o=32;o;o>>=1){ s1 += __shfl_xor(s1,o); s2 += __shfl_xor(s2,o); }
  if ((t&63)==0){ r1[t>>6]=s1; r2[t>>6]=s2; }
  __syncthreads();
  float S1 = r1[0]+r1[1], S2 = r2[0]+r2[1];
  float mu = S1*(1.f/128.f);
  float var = S2*(1.f/128.f) - mu*mu;
  out[g*CC + t] = (y - mu) * rsqrtf(var + 1e-5f);
}

extern "C" void kernel_launch(void* const* d_in, const int* in_sizes, int n_in,
                              void* d_out, int out_size, void* d_ws, size_t ws_size,
                              hipStream_t stream){
  const float* x     = (const float*)d_in[0];
  const int*   src   = (const int*)d_in[1];
  const int*   dst   = (const int*)d_in[2];
  const int*   gid   = (const int*)d_in[3];
  const float* fc1w  = (const float*)d_in[4];
  const float* al1   = (const float*)d_in[5];
  const float* ar1   = (const float*)d_in[6];
  const float* res1w = (const float*)d_in[7];
  const float* b1    = (const float*)d_in[8];
  const float* fc2w  = (const float*)d_in[9];
  const float* al2   = (const float*)d_in[10];
  const float* ar2   = (const float*)d_in[11];
  const float* b2    = (const float*)d_in[12];
  const float* aww   = (const float*)d_in[13];
  const float* awb   = (const float*)d_in[14];
  const float* outw  = (const float*)d_in[15];
  const float* outb  = (const float*)d_in[16];
  float* out = (float*)d_out;

  char* w = (char*)d_ws;
  float*          acc   = (float*)w;           w += (size_t)NN*CC*4;   // 51.2MB
  unsigned short* featb = (unsigned short*)w;  w += (size_t)NN*CC*2;   // 25.6MB
  unsigned short* hb    = (unsigned short*)w;  w += (size_t)NN*CC*2;   // 25.6MB
  float*          el    = (float*)w;           w += (size_t)NN*HH*4;
  float*          er    = (float*)w;           w += (size_t)NN*HH*4;
  float*          sumg  = (float*)w;           w += (size_t)GG*DD*4;
  unsigned*       maxg  = (unsigned*)w;        w += (size_t)GG*DD*4;
  int*            deg   = (int*)w;             w += (size_t)NN*4;
  int*            rowptr= (int*)w;             w += (size_t)(NN+1)*4;
  int*            cursor= (int*)w;             w += (size_t)NN*4;
  int*            bsum  = (int*)w;             w += 128*4;
  int*            csr   = (int*)w;             w += (size_t)EE*4;
  unsigned short* wb2   = (unsigned short*)w;  w += (size_t)CC*CC*2;

  const int EB = (EE + 255)/256;

  // CSR build + weight convert
  k_init0<<<512,256,0,stream>>>(deg, sumg, maxg);
  k_count<<<EB,256,0,stream>>>(dst, deg);
  k_scan_local<<<NB,256,0,stream>>>(deg, rowptr, bsum);
  k_scan_bsums<<<1,64,0,stream>>>(bsum, rowptr);
  k_scan_add<<<NB,256,0,stream>>>(rowptr, bsum, cursor);
  k_scatter<<<EB,256,0,stream>>>(src, dst, cursor, csr);
  k_cvtw2<<<(CC*CC+255)/256,256,0,stream>>>(fc2w, wb2);

  // layer 1
  k_feat1<<<1250,128,0,stream>>>(x, fc1w, res1w, b1, al1, ar1, featb, acc, el, er);
  k_aggr1<<<(NN+7)/8,256,0,stream>>>(rowptr, csr, el, er, featb, acc, b2, hb);
  // layer 2
  k_feat2<<<(NN/16*2+3)/4,256,0,stream>>>(hb, wb2, al2, ar2, featb, el, er);
  k_aggr2<<<(NN+7)/8,256,0,stream>>>(rowptr, csr, el, er, featb, acc, gid, aww, awb, sumg, maxg);
  // output
  k_out<<<GG,128,0,stream>>>(sumg, maxg, outw, outb, out);
}

// Round 10
// 237.505 us; speedup vs baseline: 8.5369x; 1.5388x over previous
//
#include <hip/hip_runtime.h>
#include <math.h>

#define NN 100000
#define EE 400000
#define GG 4096
#define INF_ 27
#define CC 128   // H*D
#define HH 4
#define DD 32
#define NB 98    // ceil(NN/1024) scan blocks

typedef short bf16x8 __attribute__((ext_vector_type(8)));
typedef float f32x4 __attribute__((ext_vector_type(4)));

// ---- bf16 helpers (RNE) ----
static __device__ __forceinline__ unsigned short f2bf(float f){
  unsigned u = __float_as_uint(f);
  u += 0x7fffu + ((u>>16)&1u);
  return (unsigned short)(u>>16);
}
static __device__ __forceinline__ float bf2f(unsigned short s){
  return __uint_as_float(((unsigned)s)<<16);
}

// ---- init: zero degree counts ----
__global__ void k_init0(int* __restrict__ deg){
  int i = blockIdx.x*blockDim.x + threadIdx.x;
  if (i < NN) deg[i]=0;
}

__global__ void k_count(const int* __restrict__ dst, int* __restrict__ deg){
  int i = blockIdx.x*blockDim.x + threadIdx.x;
  if (i < EE) atomicAdd(&deg[dst[i]], 1);
}

__global__ __launch_bounds__(256) void k_scan_local(const int* __restrict__ deg,
                                                    int* __restrict__ rowptr,
                                                    int* __restrict__ bsum){
  __shared__ int sh[256];
  int t = threadIdx.x;
  int idx = blockIdx.x*1024 + t*4;
  int v0 = (idx+0<NN)?deg[idx+0]:0;
  int v1 = (idx+1<NN)?deg[idx+1]:0;
  int v2 = (idx+2<NN)?deg[idx+2]:0;
  int v3 = (idx+3<NN)?deg[idx+3]:0;
  sh[t] = v0+v1+v2+v3;
  __syncthreads();
  for (int o=1;o<256;o<<=1){
    int x = (t>=o)? sh[t-o] : 0;
    __syncthreads();
    sh[t] += x;
    __syncthreads();
  }
  int run = (t==0)? 0 : sh[t-1];
  if (t==255) bsum[blockIdx.x] = sh[255];
  if (idx+0<NN){ rowptr[idx+0]=run; run+=v0; }
  if (idx+1<NN){ rowptr[idx+1]=run; run+=v1; }
  if (idx+2<NN){ rowptr[idx+2]=run; run+=v2; }
  if (idx+3<NN){ rowptr[idx+3]=run; }
}

__global__ void k_scan_bsums(int* __restrict__ bsum, int* __restrict__ rowptr){
  if (threadIdx.x==0 && blockIdx.x==0){
    int run = 0;
    for (int b=0;b<NB;b++){ int v=bsum[b]; bsum[b]=run; run+=v; }
    rowptr[NN] = run;
  }
}

__global__ __launch_bounds__(256) void k_scan_add(int* __restrict__ rowptr,
                                                  const int* __restrict__ bsum,
                                                  int* __restrict__ cursor){
  int idx = blockIdx.x*1024 + threadIdx.x*4;
  int off = bsum[blockIdx.x];
  #pragma unroll
  for (int i=0;i<4;i++){
    if (idx+i<NN){ int r = rowptr[idx+i]+off; rowptr[idx+i]=r; cursor[idx+i]=r; }
  }
}

__global__ void k_scatter(const int* __restrict__ src, const int* __restrict__ dst,
                          int* __restrict__ cursor, int* __restrict__ csr_src){
  int i = blockIdx.x*blockDim.x + threadIdx.x;
  if (i < EE){
    int pos = atomicAdd(&cursor[dst[i]], 1);
    csr_src[pos] = src[i];
  }
}

// ---- graph boundaries: gptr[g] = first node index with gid >= g ----
__global__ void k_graph_ptr(const int* __restrict__ gid, int* __restrict__ gptr){
  int i = blockIdx.x*blockDim.x + threadIdx.x;
  if (i >= NN) return;
  int g = gid[i];
  int gp = (i==0) ? -1 : gid[i-1];
  for (int q=gp+1; q<=g; q++) gptr[q] = i;
  if (i==NN-1){
    for (int q=g+1; q<=GG; q++) gptr[q] = NN;
  }
}

// ---- fc2 weights -> bf16 ----
__global__ void k_cvtw2(const float* __restrict__ w, unsigned short* __restrict__ wb){
  int i = blockIdx.x*256 + threadIdx.x;
  if (i < CC*CC) wb[i] = f2bf(w[i]);
}

// ---- layer1: featb = bf16(x@fc1^T), resb = bf16(x@res1^T + b1), el/er ----
__global__ __launch_bounds__(128) void k_feat1(
    const float* __restrict__ x, const float* __restrict__ fcw,
    const float* __restrict__ resw, const float* __restrict__ bias,
    const float* __restrict__ al, const float* __restrict__ ar,
    unsigned short* __restrict__ featb, unsigned short* __restrict__ resb,
    float* __restrict__ el, float* __restrict__ er)
{
  __shared__ float xs[8*INF_];
  const int t = threadIdx.x;
  float w1r[INF_], w2r[INF_];
  #pragma unroll
  for (int k=0;k<INF_;k++){ w1r[k]=fcw[t*INF_+k]; w2r[k]=resw[t*INF_+k]; }
  const float alv = al[t], arv = ar[t], bv = bias[t];
  for (int base = blockIdx.x*8; base < NN; base += gridDim.x*8){
    __syncthreads();
    int nb = min(8, NN-base);
    int cnt = nb*INF_;
    for (int i=t;i<cnt;i+=128) xs[i] = x[base*INF_ + i];
    __syncthreads();
    for (int i=0;i<nb;i++){
      int n = base+i;
      float vf=0.f, vr=0.f;
      #pragma unroll
      for (int k=0;k<INF_;k++){
        float xv = xs[i*INF_+k];
        vf = fmaf(xv, w1r[k], vf);
        vr = fmaf(xv, w2r[k], vr);
      }
      featb[(size_t)n*CC+t] = f2bf(vf);
      resb[(size_t)n*CC+t]  = f2bf(vr + bv);
      float la = vf*alv, ra = vf*arv;
      #pragma unroll
      for (int o=16;o;o>>=1){ la += __shfl_xor(la,o,32); ra += __shfl_xor(ra,o,32); }
      if ((t&31)==0){ el[n*HH+(t>>5)] = la; er[n*HH+(t>>5)] = ra; }
    }
  }
}

// ---- layer2 GEMM via MFMA: featb = bf16(hb @ fc2^T), el/er dots ----
__global__ __launch_bounds__(256) void k_feat2(
    const unsigned short* __restrict__ hb, const unsigned short* __restrict__ wb2,
    const float* __restrict__ al, const float* __restrict__ ar,
    unsigned short* __restrict__ featb, float* __restrict__ el, float* __restrict__ er)
{
  int wid = (blockIdx.x*256 + threadIdx.x) >> 6;
  int lane = threadIdx.x & 63;
  int tile = wid >> 1;
  int ch = wid & 1;
  if (tile >= NN/16) return;
  int l15 = lane & 15, khi = lane >> 4;
  int n0 = tile*16;
  bf16x8 wf[4][4];
  #pragma unroll
  for (int ct=0; ct<4; ct++)
    #pragma unroll
    for (int ks=0; ks<4; ks++)
      wf[ct][ks] = *(const bf16x8*)(wb2 + (size_t)(ch*64+ct*16+l15)*CC + ks*32 + khi*8);
  bf16x8 af[4];
  #pragma unroll
  for (int ks=0; ks<4; ks++)
    af[ks] = *(const bf16x8*)(hb + (size_t)(n0+l15)*CC + ks*32 + khi*8);
  f32x4 accf[4] = {{0.f,0.f,0.f,0.f},{0.f,0.f,0.f,0.f},{0.f,0.f,0.f,0.f},{0.f,0.f,0.f,0.f}};
  #pragma unroll
  for (int ks=0; ks<4; ks++)
    #pragma unroll
    for (int ct=0; ct<4; ct++)
      accf[ct] = __builtin_amdgcn_mfma_f32_16x16x32_bf16(af[ks], wf[ct][ks], accf[ct], 0,0,0);
  #pragma unroll
  for (int ct=0; ct<4; ct++)
    #pragma unroll
    for (int r=0;r<4;r++)
      featb[(size_t)(n0+khi*4+r)*CC + ch*64+ct*16+l15] = f2bf(accf[ct][r]);
  #pragma unroll
  for (int hh=0; hh<2; hh++){
    int c0 = ch*64 + hh*32 + l15;
    float a0 = al[c0], a1 = al[c0+16], b0 = ar[c0], b1 = ar[c0+16];
    #pragma unroll
    for (int r=0;r<4;r++){
      float pe = accf[2*hh][r]*a0 + accf[2*hh+1][r]*a1;
      float pr = accf[2*hh][r]*b0 + accf[2*hh+1][r]*b1;
      #pragma unroll
      for (int o=8;o;o>>=1){ pe += __shfl_xor(pe,o,16); pr += __shfl_xor(pr,o,16); }
      if (l15==0){
        int n = n0 + khi*4 + r;
        el[n*HH + ch*2+hh] = pe;
        er[n*HH + ch*2+hh] = pr;
      }
    }
  }
}

// ---- layer1 aggregation: single fused softmax pass (no max-subtract),
//      epilogue elu(res + rst) -> hb(bf16). half-wave per node. ----
__global__ __launch_bounds__(256) void k_aggr1(
    const int* __restrict__ rowptr, const int* __restrict__ csr,
    const float* __restrict__ el, const float* __restrict__ er,
    const unsigned short* __restrict__ featb,
    const unsigned short* __restrict__ resb,
    unsigned short* __restrict__ hb)
{
  int t = threadIdx.x;
  int n = blockIdx.x*8 + (t>>5);
  if (n >= NN) return;
  int lane = t & 31;
  int h = lane >> 3;
  int e0 = rowptr[n], e1 = rowptr[n+1];
  float ern = er[n*HH + h];
  float ssum = 0.f;
  float r0=0.f,r1=0.f,r2=0.f,r3=0.f;
  int j = e0;
  for (; j+2 <= e1; j += 2){
    int sa = csr[j], sb = csr[j+1];
    float va = el[sa*HH+h] + ern; va = va>0.f?va:0.2f*va;
    float vb = el[sb*HH+h] + ern; vb = vb>0.f?vb:0.2f*vb;
    float aa = __expf(va), ab = __expf(vb);
    ssum += aa + ab;
    ushort4 fa = *(const ushort4*)(featb + (size_t)sa*CC + lane*4);
    ushort4 fb = *(const ushort4*)(featb + (size_t)sb*CC + lane*4);
    r0 = fmaf(bf2f(fa.x), aa, r0); r1 = fmaf(bf2f(fa.y), aa, r1);
    r2 = fmaf(bf2f(fa.z), aa, r2); r3 = fmaf(bf2f(fa.w), aa, r3);
    r0 = fmaf(bf2f(fb.x), ab, r0); r1 = fmaf(bf2f(fb.y), ab, r1);
    r2 = fmaf(bf2f(fb.z), ab, r2); r3 = fmaf(bf2f(fb.w), ab, r3);
  }
  if (j < e1){
    int sa = csr[j];
    float va = el[sa*HH+h] + ern; va = va>0.f?va:0.2f*va;
    float aa = __expf(va);
    ssum += aa;
    ushort4 fa = *(const ushort4*)(featb + (size_t)sa*CC + lane*4);
    r0 = fmaf(bf2f(fa.x), aa, r0); r1 = fmaf(bf2f(fa.y), aa, r1);
    r2 = fmaf(bf2f(fa.z), aa, r2); r3 = fmaf(bf2f(fa.w), aa, r3);
  }
  float inv = (e1 > e0) ? 1.f/ssum : 0.f;
  ushort4 rv = *(const ushort4*)(resb + (size_t)n*CC + lane*4);
  float t0 = bf2f(rv.x) + r0*inv;
  float t1 = bf2f(rv.y) + r1*inv;
  float t2 = bf2f(rv.z) + r2*inv;
  float t3 = bf2f(rv.w) + r3*inv;
  t0 = t0 > 0.f ? t0 : __expf(t0)-1.f;
  t1 = t1 > 0.f ? t1 : __expf(t1)-1.f;
  t2 = t2 > 0.f ? t2 : __expf(t2)-1.f;
  t3 = t3 > 0.f ? t3 : __expf(t3)-1.f;
  ushort4 hb4; hb4.x=f2bf(t0); hb4.y=f2bf(t1); hb4.z=f2bf(t2); hb4.w=f2bf(t3);
  *(ushort4*)(hb + (size_t)n*CC + lane*4) = hb4;
}

// ---- layer2 aggregation + readout + output: ONE BLOCK PER GRAPH ----
// 8 half-wave groups each handle one node at a time; graph sum/max in regs,
// LDS-combined, then y=g@out_w^T+b and LayerNorm, all in-block. No atomics.
__global__ __launch_bounds__(256) void k_aggr2(
    const int* __restrict__ gptr, const int* __restrict__ rowptr,
    const int* __restrict__ csr,
    const float* __restrict__ el, const float* __restrict__ er,
    const unsigned short* __restrict__ featb,
    const unsigned short* __restrict__ hb,
    const float* __restrict__ b2, const float* __restrict__ aww,
    const float* __restrict__ awb,
    const float* __restrict__ outw, const float* __restrict__ outb,
    float* __restrict__ out)
{
  __shared__ float lsum[8][32];
  __shared__ float lmax[8][32];
  __shared__ float gv[64];
  __shared__ float rr1[2], rr2[2];
  int g = blockIdx.x;
  int n0 = gptr[g], n1 = gptr[g+1];
  int t = threadIdx.x;
  int grp = t>>5, lane = t&31, h = lane>>3;
  float gs0=0.f,gs1=0.f,gs2=0.f,gs3=0.f;
  float gm0=-3.4e38f,gm1=-3.4e38f,gm2=-3.4e38f,gm3=-3.4e38f;
  float4 bv  = *(const float4*)(b2 + lane*4);
  float4 aw4 = *(const float4*)(aww + (lane&7)*4);
  float awbv = awb[0];
  for (int n = n0+grp; n < n1; n += 8){
    int e0 = rowptr[n], e1 = rowptr[n+1];
    float ern = er[n*HH + h];
    float ssum = 0.f;
    float r0=0.f,r1=0.f,r2=0.f,r3=0.f;
    int j = e0;
    for (; j+2 <= e1; j += 2){
      int sa = csr[j], sb = csr[j+1];
      float va = el[sa*HH+h] + ern; va = va>0.f?va:0.2f*va;
      float vb = el[sb*HH+h] + ern; vb = vb>0.f?vb:0.2f*vb;
      float aa = __expf(va), ab = __expf(vb);
      ssum += aa + ab;
      ushort4 fa = *(const ushort4*)(featb + (size_t)sa*CC + lane*4);
      ushort4 fb = *(const ushort4*)(featb + (size_t)sb*CC + lane*4);
      r0 = fmaf(bf2f(fa.x), aa, r0); r1 = fmaf(bf2f(fa.y), aa, r1);
      r2 = fmaf(bf2f(fa.z), aa, r2); r3 = fmaf(bf2f(fa.w), aa, r3);
      r0 = fmaf(bf2f(fb.x), ab, r0); r1 = fmaf(bf2f(fb.y), ab, r1);
      r2 = fmaf(bf2f(fb.z), ab, r2); r3 = fmaf(bf2f(fb.w), ab, r3);
    }
    if (j < e1){
      int sa = csr[j];
      float va = el[sa*HH+h] + ern; va = va>0.f?va:0.2f*va;
      float aa = __expf(va);
      ssum += aa;
      ushort4 fa = *(const ushort4*)(featb + (size_t)sa*CC + lane*4);
      r0 = fmaf(bf2f(fa.x), aa, r0); r1 = fmaf(bf2f(fa.y), aa, r1);
      r2 = fmaf(bf2f(fa.z), aa, r2); r3 = fmaf(bf2f(fa.w), aa, r3);
    }
    float inv = (e1 > e0) ? 1.f/ssum : 0.f;
    ushort4 hv = *(const ushort4*)(hb + (size_t)n*CC + lane*4);
    float t0 = bf2f(hv.x) + bv.x + r0*inv;
    float t1 = bf2f(hv.y) + bv.y + r1*inv;
    float t2 = bf2f(hv.z) + bv.z + r2*inv;
    float t3 = bf2f(hv.w) + bv.w + r3*inv;
    // head-mean across the 4 head groups (xor 8, 16 within 32)
    float s0=t0,s1=t1,s2=t2,s3=t3;
    s0 += __shfl_xor(s0,8,32);  s1 += __shfl_xor(s1,8,32);
    s2 += __shfl_xor(s2,8,32);  s3 += __shfl_xor(s3,8,32);
    s0 += __shfl_xor(s0,16,32); s1 += __shfl_xor(s1,16,32);
    s2 += __shfl_xor(s2,16,32); s3 += __shfl_xor(s3,16,32);
    float hm0=0.25f*s0, hm1=0.25f*s1, hm2=0.25f*s2, hm3=0.25f*s3;
    float p = hm0*aw4.x + hm1*aw4.y + hm2*aw4.z + hm3*aw4.w;
    p += __shfl_xor(p,1,32); p += __shfl_xor(p,2,32); p += __shfl_xor(p,4,32);
    float wgt = 1.f/(1.f + __expf(-(p + awbv)));
    gs0 = fmaf(wgt, hm0, gs0); gs1 = fmaf(wgt, hm1, gs1);
    gs2 = fmaf(wgt, hm2, gs2); gs3 = fmaf(wgt, hm3, gs3);
    gm0 = fmaxf(gm0, hm0); gm1 = fmaxf(gm1, hm1);
    gm2 = fmaxf(gm2, hm2); gm3 = fmaxf(gm3, hm3);
  }
  if (lane < 8){
    int c = lane*4;
    lsum[grp][c+0]=gs0; lsum[grp][c+1]=gs1; lsum[grp][c+2]=gs2; lsum[grp][c+3]=gs3;
    lmax[grp][c+0]=gm0; lmax[grp][c+1]=gm1; lmax[grp][c+2]=gm2; lmax[grp][c+3]=gm3;
  }
  __syncthreads();
  if (t < 32){
    float s=0.f, m=-3.4e38f;
    #pragma unroll
    for (int q=0;q<8;q++){ s += lsum[q][t]; m = fmaxf(m, lmax[q][t]); }
    gv[t]    = s;
    gv[32+t] = (m < -3.0e38f) ? 0.f : m;
  }
  __syncthreads();
  float y = 0.f;
  if (t < 128){
    y = outb[t];
    #pragma unroll
    for (int jj=0;jj<64;jj++) y = fmaf(gv[jj], outw[t*64+jj], y);
    float s1 = y, s2 = y*y;
    #pragma unroll
    for (int o=32;o;o>>=1){ s1 += __shfl_xor(s1,o); s2 += __shfl_xor(s2,o); }
    if ((t&63)==0){ rr1[t>>6]=s1; rr2[t>>6]=s2; }
  }
  __syncthreads();
  if (t < 128){
    float S1 = rr1[0]+rr1[1], S2 = rr2[0]+rr2[1];
    float mu = S1*(1.f/128.f);
    float var = S2*(1.f/128.f) - mu*mu;
    out[g*CC + t] = (y - mu) * rsqrtf(var + 1e-5f);
  }
}

extern "C" void kernel_launch(void* const* d_in, const int* in_sizes, int n_in,
                              void* d_out, int out_size, void* d_ws, size_t ws_size,
                              hipStream_t stream){
  const float* x     = (const float*)d_in[0];
  const int*   src   = (const int*)d_in[1];
  const int*   dst   = (const int*)d_in[2];
  const int*   gid   = (const int*)d_in[3];
  const float* fc1w  = (const float*)d_in[4];
  const float* al1   = (const float*)d_in[5];
  const float* ar1   = (const float*)d_in[6];
  const float* res1w = (const float*)d_in[7];
  const float* b1    = (const float*)d_in[8];
  const float* fc2w  = (const float*)d_in[9];
  const float* al2   = (const float*)d_in[10];
  const float* ar2   = (const float*)d_in[11];
  const float* b2    = (const float*)d_in[12];
  const float* aww   = (const float*)d_in[13];
  const float* awb   = (const float*)d_in[14];
  const float* outw  = (const float*)d_in[15];
  const float* outb  = (const float*)d_in[16];
  float* out = (float*)d_out;

  char* w = (char*)d_ws;
  unsigned short* featb = (unsigned short*)w;  w += (size_t)NN*CC*2;   // 25.6MB
  unsigned short* hb    = (unsigned short*)w;  w += (size_t)NN*CC*2;   // 25.6MB
  unsigned short* resb  = (unsigned short*)w;  w += (size_t)NN*CC*2;   // 25.6MB
  float*          el    = (float*)w;           w += (size_t)NN*HH*4;
  float*          er    = (float*)w;           w += (size_t)NN*HH*4;
  int*            deg   = (int*)w;             w += (size_t)NN*4;
  int*            rowptr= (int*)w;             w += (size_t)(NN+1)*4;
  int*            cursor= (int*)w;             w += (size_t)NN*4;
  int*            bsum  = (int*)w;             w += 128*4;
  int*            csr   = (int*)w;             w += (size_t)EE*4;
  int*            gptr  = (int*)w;             w += (size_t)(GG+1)*4;
  unsigned short* wb2   = (unsigned short*)w;  w += (size_t)CC*CC*2;

  const int EB = (EE + 255)/256;
  const int NBK = (NN + 255)/256;

  // CSR + graph-boundary build + weight convert
  k_init0<<<NBK,256,0,stream>>>(deg);
  k_count<<<EB,256,0,stream>>>(dst, deg);
  k_scan_local<<<NB,256,0,stream>>>(deg, rowptr, bsum);
  k_scan_bsums<<<1,64,0,stream>>>(bsum, rowptr);
  k_scan_add<<<NB,256,0,stream>>>(rowptr, bsum, cursor);
  k_scatter<<<EB,256,0,stream>>>(src, dst, cursor, csr);
  k_graph_ptr<<<NBK,256,0,stream>>>(gid, gptr);
  k_cvtw2<<<(CC*CC+255)/256,256,0,stream>>>(fc2w, wb2);

  // layer 1
  k_feat1<<<1250,128,0,stream>>>(x, fc1w, res1w, b1, al1, ar1, featb, resb, el, er);
  k_aggr1<<<(NN+7)/8,256,0,stream>>>(rowptr, csr, el, er, featb, resb, hb);
  // layer 2
  k_feat2<<<(NN/16*2+3)/4,256,0,stream>>>(hb, wb2, al2, ar2, featb, el, er);
  // fused aggregation + readout + gnn_last + LayerNorm (block per graph)
  k_aggr2<<<GG,256,0,stream>>>(gptr, rowptr, csr, el, er, featb, hb,
                               b2, aww, awb, outw, outb, out);
}

// Round 11
// 215.165 us; speedup vs baseline: 9.4233x; 1.1038x over previous
//
#include <hip/hip_runtime.h>
#include <math.h>

#define NN 100000
#define EE 400000
#define GG 4096
#define INF_ 27
#define CC 128   // H*D
#define HH 4
#define DD 32
#define NB 98    // ceil(NN/1024) scan blocks

typedef short bf16x8 __attribute__((ext_vector_type(8)));
typedef float f32x4 __attribute__((ext_vector_type(4)));

// ---- bf16 helpers (RNE) ----
static __device__ __forceinline__ unsigned short f2bf(float f){
  unsigned u = __float_as_uint(f);
  u += 0x7fffu + ((u>>16)&1u);
  return (unsigned short)(u>>16);
}
static __device__ __forceinline__ float bf2f(unsigned short s){
  return __uint_as_float(((unsigned)s)<<16);
}

// ---- init: zero degree counts ----
__global__ void k_init0(int* __restrict__ deg){
  int i = blockIdx.x*blockDim.x + threadIdx.x;
  if (i < NN) deg[i]=0;
}

__global__ void k_count(const int* __restrict__ dst, int* __restrict__ deg){
  int i = blockIdx.x*blockDim.x + threadIdx.x;
  if (i < EE) atomicAdd(&deg[dst[i]], 1);
}

__global__ __launch_bounds__(256) void k_scan_local(const int* __restrict__ deg,
                                                    int* __restrict__ rowptr,
                                                    int* __restrict__ bsum){
  __shared__ int sh[256];
  int t = threadIdx.x;
  int idx = blockIdx.x*1024 + t*4;
  int v0 = (idx+0<NN)?deg[idx+0]:0;
  int v1 = (idx+1<NN)?deg[idx+1]:0;
  int v2 = (idx+2<NN)?deg[idx+2]:0;
  int v3 = (idx+3<NN)?deg[idx+3]:0;
  sh[t] = v0+v1+v2+v3;
  __syncthreads();
  for (int o=1;o<256;o<<=1){
    int x = (t>=o)? sh[t-o] : 0;
    __syncthreads();
    sh[t] += x;
    __syncthreads();
  }
  int run = (t==0)? 0 : sh[t-1];
  if (t==255) bsum[blockIdx.x] = sh[255];
  if (idx+0<NN){ rowptr[idx+0]=run; run+=v0; }
  if (idx+1<NN){ rowptr[idx+1]=run; run+=v1; }
  if (idx+2<NN){ rowptr[idx+2]=run; run+=v2; }
  if (idx+3<NN){ rowptr[idx+3]=run; }
}

__global__ void k_scan_bsums(int* __restrict__ bsum, int* __restrict__ rowptr){
  if (threadIdx.x==0 && blockIdx.x==0){
    int run = 0;
    for (int b=0;b<NB;b++){ int v=bsum[b]; bsum[b]=run; run+=v; }
    rowptr[NN] = run;
  }
}

__global__ __launch_bounds__(256) void k_scan_add(int* __restrict__ rowptr,
                                                  const int* __restrict__ bsum,
                                                  int* __restrict__ cursor){
  int idx = blockIdx.x*1024 + threadIdx.x*4;
  int off = bsum[blockIdx.x];
  #pragma unroll
  for (int i=0;i<4;i++){
    if (idx+i<NN){ int r = rowptr[idx+i]+off; rowptr[idx+i]=r; cursor[idx+i]=r; }
  }
}

__global__ void k_scatter(const int* __restrict__ src, const int* __restrict__ dst,
                          int* __restrict__ cursor, int* __restrict__ csr_src){
  int i = blockIdx.x*blockDim.x + threadIdx.x;
  if (i < EE){
    int pos = atomicAdd(&cursor[dst[i]], 1);
    csr_src[pos] = src[i];
  }
}

// ---- graph boundaries: gptr[g] = first node index with gid >= g ----
__global__ void k_graph_ptr(const int* __restrict__ gid, int* __restrict__ gptr){
  int i = blockIdx.x*blockDim.x + threadIdx.x;
  if (i >= NN) return;
  int g = gid[i];
  int gp = (i==0) ? -1 : gid[i-1];
  for (int q=gp+1; q<=g; q++) gptr[q] = i;
  if (i==NN-1){
    for (int q=g+1; q<=GG; q++) gptr[q] = NN;
  }
}

// ---- fc2 weights -> bf16 ----
__global__ void k_cvtw2(const float* __restrict__ w, unsigned short* __restrict__ wb){
  int i = blockIdx.x*256 + threadIdx.x;
  if (i < CC*CC) wb[i] = f2bf(w[i]);
}

// ---- x -> bf16, K padded 27->32 ----
__global__ void k_cvtx(const float* __restrict__ x, unsigned short* __restrict__ xb){
  int i = blockIdx.x*256 + threadIdx.x;
  if (i >= NN*32) return;
  int n = i>>5, k = i&31;
  xb[i] = (k<INF_) ? f2bf(x[n*INF_+k]) : (unsigned short)0;
}

// ---- layer1 weights -> bf16, K padded 27->32 ----
__global__ void k_cvtw1(const float* __restrict__ fcw, const float* __restrict__ resw,
                        unsigned short* __restrict__ wb1, unsigned short* __restrict__ wrb){
  int i = blockIdx.x*256 + threadIdx.x;
  if (i >= CC*32) return;
  int c = i>>5, k = i&31;
  wb1[i] = (k<INF_) ? f2bf(fcw[c*INF_+k]) : (unsigned short)0;
  wrb[i] = (k<INF_) ? f2bf(resw[c*INF_+k]) : (unsigned short)0;
}

// ---- layer1 via MFMA: featb = bf16(x@fc1^T), resb = bf16(x@res1^T + b1), el/er.
//      wave = 16-node tile x all 128 cols; both weight matrices in VGPRs. ----
__global__ __launch_bounds__(256) void k_feat1m(
    const unsigned short* __restrict__ xb, const unsigned short* __restrict__ wb1,
    const unsigned short* __restrict__ wrb, const float* __restrict__ bias,
    const float* __restrict__ al, const float* __restrict__ ar,
    unsigned short* __restrict__ featb, unsigned short* __restrict__ resb,
    float* __restrict__ el, float* __restrict__ er)
{
  int wid = (blockIdx.x*256 + threadIdx.x) >> 6;
  int lane = threadIdx.x & 63;
  int l15 = lane & 15, khi = lane >> 4;
  int nw = gridDim.x*4;
  bf16x8 wf[8], wr[8];
  float bv8[8];
  #pragma unroll
  for (int ct=0; ct<8; ct++){
    wf[ct] = *(const bf16x8*)(wb1 + (ct*16+l15)*32 + khi*8);
    wr[ct] = *(const bf16x8*)(wrb + (ct*16+l15)*32 + khi*8);
    bv8[ct] = bias[ct*16+l15];
  }
  float a0v[4], a1v[4], b0v[4], b1v[4];
  #pragma unroll
  for (int hh=0; hh<4; hh++){
    int c0 = hh*32 + l15;
    a0v[hh] = al[c0]; a1v[hh] = al[c0+16];
    b0v[hh] = ar[c0]; b1v[hh] = ar[c0+16];
  }
  for (int tile = wid; tile < NN/16; tile += nw){
    int n0 = tile*16;
    bf16x8 af = *(const bf16x8*)(xb + (size_t)(n0+l15)*32 + khi*8);
    f32x4 accf[8], accr[8];
    #pragma unroll
    for (int ct=0; ct<8; ct++){
      accf[ct] = __builtin_amdgcn_mfma_f32_16x16x32_bf16(af, wf[ct], (f32x4){0.f,0.f,0.f,0.f}, 0,0,0);
      accr[ct] = __builtin_amdgcn_mfma_f32_16x16x32_bf16(af, wr[ct], (f32x4){0.f,0.f,0.f,0.f}, 0,0,0);
    }
    #pragma unroll
    for (int ct=0; ct<8; ct++){
      int c = ct*16+l15;
      #pragma unroll
      for (int r=0;r<4;r++){
        int n = n0 + khi*4 + r;
        featb[(size_t)n*CC + c] = f2bf(accf[ct][r]);
        resb [(size_t)n*CC + c] = f2bf(accr[ct][r] + bv8[ct]);
      }
    }
    #pragma unroll
    for (int hh=0; hh<4; hh++){
      #pragma unroll
      for (int r=0;r<4;r++){
        float pe = accf[2*hh][r]*a0v[hh] + accf[2*hh+1][r]*a1v[hh];
        float pr = accf[2*hh][r]*b0v[hh] + accf[2*hh+1][r]*b1v[hh];
        #pragma unroll
        for (int o=8;o;o>>=1){ pe += __shfl_xor(pe,o,16); pr += __shfl_xor(pr,o,16); }
        if (l15==0){
          int n = n0 + khi*4 + r;
          el[n*HH + hh] = pe;
          er[n*HH + hh] = pr;
        }
      }
    }
  }
}

// ---- layer2 GEMM via MFMA: featb = bf16(hb @ fc2^T), el/er dots ----
__global__ __launch_bounds__(256) void k_feat2(
    const unsigned short* __restrict__ hb, const unsigned short* __restrict__ wb2,
    const float* __restrict__ al, const float* __restrict__ ar,
    unsigned short* __restrict__ featb, float* __restrict__ el, float* __restrict__ er)
{
  int wid = (blockIdx.x*256 + threadIdx.x) >> 6;
  int lane = threadIdx.x & 63;
  int tile = wid >> 1;
  int ch = wid & 1;
  if (tile >= NN/16) return;
  int l15 = lane & 15, khi = lane >> 4;
  int n0 = tile*16;
  bf16x8 wf[4][4];
  #pragma unroll
  for (int ct=0; ct<4; ct++)
    #pragma unroll
    for (int ks=0; ks<4; ks++)
      wf[ct][ks] = *(const bf16x8*)(wb2 + (size_t)(ch*64+ct*16+l15)*CC + ks*32 + khi*8);
  bf16x8 af[4];
  #pragma unroll
  for (int ks=0; ks<4; ks++)
    af[ks] = *(const bf16x8*)(hb + (size_t)(n0+l15)*CC + ks*32 + khi*8);
  f32x4 accf[4] = {{0.f,0.f,0.f,0.f},{0.f,0.f,0.f,0.f},{0.f,0.f,0.f,0.f},{0.f,0.f,0.f,0.f}};
  #pragma unroll
  for (int ks=0; ks<4; ks++)
    #pragma unroll
    for (int ct=0; ct<4; ct++)
      accf[ct] = __builtin_amdgcn_mfma_f32_16x16x32_bf16(af[ks], wf[ct][ks], accf[ct], 0,0,0);
  #pragma unroll
  for (int ct=0; ct<4; ct++)
    #pragma unroll
    for (int r=0;r<4;r++)
      featb[(size_t)(n0+khi*4+r)*CC + ch*64+ct*16+l15] = f2bf(accf[ct][r]);
  #pragma unroll
  for (int hh=0; hh<2; hh++){
    int c0 = ch*64 + hh*32 + l15;
    float a0 = al[c0], a1 = al[c0+16], b0 = ar[c0], b1 = ar[c0+16];
    #pragma unroll
    for (int r=0;r<4;r++){
      float pe = accf[2*hh][r]*a0 + accf[2*hh+1][r]*a1;
      float pr = accf[2*hh][r]*b0 + accf[2*hh+1][r]*b1;
      #pragma unroll
      for (int o=8;o;o>>=1){ pe += __shfl_xor(pe,o,16); pr += __shfl_xor(pr,o,16); }
      if (l15==0){
        int n = n0 + khi*4 + r;
        el[n*HH + ch*2+hh] = pe;
        er[n*HH + ch*2+hh] = pr;
      }
    }
  }
}

// ---- layer1 aggregation: single fused softmax pass (no max-subtract),
//      epilogue elu(res + rst) -> hb(bf16). half-wave per node. ----
__global__ __launch_bounds__(256) void k_aggr1(
    const int* __restrict__ rowptr, const int* __restrict__ csr,
    const float* __restrict__ el, const float* __restrict__ er,
    const unsigned short* __restrict__ featb,
    const unsigned short* __restrict__ resb,
    unsigned short* __restrict__ hb)
{
  int t = threadIdx.x;
  int n = blockIdx.x*8 + (t>>5);
  if (n >= NN) return;
  int lane = t & 31;
  int h = lane >> 3;
  int e0 = rowptr[n], e1 = rowptr[n+1];
  float ern = er[n*HH + h];
  float ssum = 0.f;
  float r0=0.f,r1=0.f,r2=0.f,r3=0.f;
  int j = e0;
  for (; j+2 <= e1; j += 2){
    int sa = csr[j], sb = csr[j+1];
    float va = el[sa*HH+h] + ern; va = va>0.f?va:0.2f*va;
    float vb = el[sb*HH+h] + ern; vb = vb>0.f?vb:0.2f*vb;
    float aa = __expf(va), ab = __expf(vb);
    ssum += aa + ab;
    ushort4 fa = *(const ushort4*)(featb + (size_t)sa*CC + lane*4);
    ushort4 fb = *(const ushort4*)(featb + (size_t)sb*CC + lane*4);
    r0 = fmaf(bf2f(fa.x), aa, r0); r1 = fmaf(bf2f(fa.y), aa, r1);
    r2 = fmaf(bf2f(fa.z), aa, r2); r3 = fmaf(bf2f(fa.w), aa, r3);
    r0 = fmaf(bf2f(fb.x), ab, r0); r1 = fmaf(bf2f(fb.y), ab, r1);
    r2 = fmaf(bf2f(fb.z), ab, r2); r3 = fmaf(bf2f(fb.w), ab, r3);
  }
  if (j < e1){
    int sa = csr[j];
    float va = el[sa*HH+h] + ern; va = va>0.f?va:0.2f*va;
    float aa = __expf(va);
    ssum += aa;
    ushort4 fa = *(const ushort4*)(featb + (size_t)sa*CC + lane*4);
    r0 = fmaf(bf2f(fa.x), aa, r0); r1 = fmaf(bf2f(fa.y), aa, r1);
    r2 = fmaf(bf2f(fa.z), aa, r2); r3 = fmaf(bf2f(fa.w), aa, r3);
  }
  float inv = (e1 > e0) ? 1.f/ssum : 0.f;
  ushort4 rv = *(const ushort4*)(resb + (size_t)n*CC + lane*4);
  float t0 = bf2f(rv.x) + r0*inv;
  float t1 = bf2f(rv.y) + r1*inv;
  float t2 = bf2f(rv.z) + r2*inv;
  float t3 = bf2f(rv.w) + r3*inv;
  t0 = t0 > 0.f ? t0 : __expf(t0)-1.f;
  t1 = t1 > 0.f ? t1 : __expf(t1)-1.f;
  t2 = t2 > 0.f ? t2 : __expf(t2)-1.f;
  t3 = t3 > 0.f ? t3 : __expf(t3)-1.f;
  ushort4 hb4; hb4.x=f2bf(t0); hb4.y=f2bf(t1); hb4.z=f2bf(t2); hb4.w=f2bf(t3);
  *(ushort4*)(hb + (size_t)n*CC + lane*4) = hb4;
}

// ---- layer2 aggregation + readout + output: ONE BLOCK PER GRAPH ----
__global__ __launch_bounds__(256) void k_aggr2(
    const int* __restrict__ gptr, const int* __restrict__ rowptr,
    const int* __restrict__ csr,
    const float* __restrict__ el, const float* __restrict__ er,
    const unsigned short* __restrict__ featb,
    const unsigned short* __restrict__ hb,
    const float* __restrict__ b2, const float* __restrict__ aww,
    const float* __restrict__ awb,
    const float* __restrict__ outw, const float* __restrict__ outb,
    float* __restrict__ out)
{
  __shared__ float lsum[8][32];
  __shared__ float lmax[8][32];
  __shared__ float gv[64];
  __shared__ float rr1[2], rr2[2];
  int g = blockIdx.x;
  int n0 = gptr[g], n1 = gptr[g+1];
  int t = threadIdx.x;
  int grp = t>>5, lane = t&31, h = lane>>3;
  float gs0=0.f,gs1=0.f,gs2=0.f,gs3=0.f;
  float gm0=-3.4e38f,gm1=-3.4e38f,gm2=-3.4e38f,gm3=-3.4e38f;
  float4 bv  = *(const float4*)(b2 + lane*4);
  float4 aw4 = *(const float4*)(aww + (lane&7)*4);
  float awbv = awb[0];
  for (int n = n0+grp; n < n1; n += 8){
    int e0 = rowptr[n], e1 = rowptr[n+1];
    float ern = er[n*HH + h];
    float ssum = 0.f;
    float r0=0.f,r1=0.f,r2=0.f,r3=0.f;
    int j = e0;
    for (; j+2 <= e1; j += 2){
      int sa = csr[j], sb = csr[j+1];
      float va = el[sa*HH+h] + ern; va = va>0.f?va:0.2f*va;
      float vb = el[sb*HH+h] + ern; vb = vb>0.f?vb:0.2f*vb;
      float aa = __expf(va), ab = __expf(vb);
      ssum += aa + ab;
      ushort4 fa = *(const ushort4*)(featb + (size_t)sa*CC + lane*4);
      ushort4 fb = *(const ushort4*)(featb + (size_t)sb*CC + lane*4);
      r0 = fmaf(bf2f(fa.x), aa, r0); r1 = fmaf(bf2f(fa.y), aa, r1);
      r2 = fmaf(bf2f(fa.z), aa, r2); r3 = fmaf(bf2f(fa.w), aa, r3);
      r0 = fmaf(bf2f(fb.x), ab, r0); r1 = fmaf(bf2f(fb.y), ab, r1);
      r2 = fmaf(bf2f(fb.z), ab, r2); r3 = fmaf(bf2f(fb.w), ab, r3);
    }
    if (j < e1){
      int sa = csr[j];
      float va = el[sa*HH+h] + ern; va = va>0.f?va:0.2f*va;
      float aa = __expf(va);
      ssum += aa;
      ushort4 fa = *(const ushort4*)(featb + (size_t)sa*CC + lane*4);
      r0 = fmaf(bf2f(fa.x), aa, r0); r1 = fmaf(bf2f(fa.y), aa, r1);
      r2 = fmaf(bf2f(fa.z), aa, r2); r3 = fmaf(bf2f(fa.w), aa, r3);
    }
    float inv = (e1 > e0) ? 1.f/ssum : 0.f;
    ushort4 hv = *(const ushort4*)(hb + (size_t)n*CC + lane*4);
    float t0 = bf2f(hv.x) + bv.x + r0*inv;
    float t1 = bf2f(hv.y) + bv.y + r1*inv;
    float t2 = bf2f(hv.z) + bv.z + r2*inv;
    float t3 = bf2f(hv.w) + bv.w + r3*inv;
    float s0=t0,s1=t1,s2=t2,s3=t3;
    s0 += __shfl_xor(s0,8,32);  s1 += __shfl_xor(s1,8,32);
    s2 += __shfl_xor(s2,8,32);  s3 += __shfl_xor(s3,8,32);
    s0 += __shfl_xor(s0,16,32); s1 += __shfl_xor(s1,16,32);
    s2 += __shfl_xor(s2,16,32); s3 += __shfl_xor(s3,16,32);
    float hm0=0.25f*s0, hm1=0.25f*s1, hm2=0.25f*s2, hm3=0.25f*s3;
    float p = hm0*aw4.x + hm1*aw4.y + hm2*aw4.z + hm3*aw4.w;
    p += __shfl_xor(p,1,32); p += __shfl_xor(p,2,32); p += __shfl_xor(p,4,32);
    float wgt = 1.f/(1.f + __expf(-(p + awbv)));
    gs0 = fmaf(wgt, hm0, gs0); gs1 = fmaf(wgt, hm1, gs1);
    gs2 = fmaf(wgt, hm2, gs2); gs3 = fmaf(wgt, hm3, gs3);
    gm0 = fmaxf(gm0, hm0); gm1 = fmaxf(gm1, hm1);
    gm2 = fmaxf(gm2, hm2); gm3 = fmaxf(gm3, hm3);
  }
  if (lane < 8){
    int c = lane*4;
    lsum[grp][c+0]=gs0; lsum[grp][c+1]=gs1; lsum[grp][c+2]=gs2; lsum[grp][c+3]=gs3;
    lmax[grp][c+0]=gm0; lmax[grp][c+1]=gm1; lmax[grp][c+2]=gm2; lmax[grp][c+3]=gm3;
  }
  __syncthreads();
  if (t < 32){
    float s=0.f, m=-3.4e38f;
    #pragma unroll
    for (int q=0;q<8;q++){ s += lsum[q][t]; m = fmaxf(m, lmax[q][t]); }
    gv[t]    = s;
    gv[32+t] = (m < -3.0e38f) ? 0.f : m;
  }
  __syncthreads();
  float y = 0.f;
  if (t < 128){
    y = outb[t];
    #pragma unroll
    for (int jj=0;jj<64;jj++) y = fmaf(gv[jj], outw[t*64+jj], y);
    float s1 = y, s2 = y*y;
    #pragma unroll
    for (int o=32;o;o>>=1){ s1 += __shfl_xor(s1,o); s2 += __shfl_xor(s2,o); }
    if ((t&63)==0){ rr1[t>>6]=s1; rr2[t>>6]=s2; }
  }
  __syncthreads();
  if (t < 128){
    float S1 = rr1[0]+rr1[1], S2 = rr2[0]+rr2[1];
    float mu = S1*(1.f/128.f);
    float var = S2*(1.f/128.f) - mu*mu;
    out[g*CC + t] = (y - mu) * rsqrtf(var + 1e-5f);
  }
}

extern "C" void kernel_launch(void* const* d_in, const int* in_sizes, int n_in,
                              void* d_out, int out_size, void* d_ws, size_t ws_size,
                              hipStream_t stream){
  const float* x     = (const float*)d_in[0];
  const int*   src   = (const int*)d_in[1];
  const int*   dst   = (const int*)d_in[2];
  const int*   gid   = (const int*)d_in[3];
  const float* fc1w  = (const float*)d_in[4];
  const float* al1   = (const float*)d_in[5];
  const float* ar1   = (const float*)d_in[6];
  const float* res1w = (const float*)d_in[7];
  const float* b1    = (const float*)d_in[8];
  const float* fc2w  = (const float*)d_in[9];
  const float* al2   = (const float*)d_in[10];
  const float* ar2   = (const float*)d_in[11];
  const float* b2    = (const float*)d_in[12];
  const float* aww   = (const float*)d_in[13];
  const float* awb   = (const float*)d_in[14];
  const float* outw  = (const float*)d_in[15];
  const float* outb  = (const float*)d_in[16];
  float* out = (float*)d_out;

  char* w = (char*)d_ws;
  unsigned short* featb = (unsigned short*)w;  w += (size_t)NN*CC*2;   // 25.6MB
  unsigned short* hb    = (unsigned short*)w;  w += (size_t)NN*CC*2;   // 25.6MB
  unsigned short* resb  = (unsigned short*)w;  w += (size_t)NN*CC*2;   // 25.6MB
  float*          el    = (float*)w;           w += (size_t)NN*HH*4;
  float*          er    = (float*)w;           w += (size_t)NN*HH*4;
  int*            deg   = (int*)w;             w += (size_t)NN*4;
  int*            rowptr= (int*)w;             w += (size_t)(NN+1)*4;
  int*            cursor= (int*)w;             w += (size_t)NN*4;
  int*            bsum  = (int*)w;             w += 128*4;
  int*            csr   = (int*)w;             w += (size_t)EE*4;
  int*            gptr  = (int*)w;             w += (size_t)(GG+1)*4;
  unsigned short* wb2   = (unsigned short*)w;  w += (size_t)CC*CC*2;
  unsigned short* xb    = (unsigned short*)w;  w += (size_t)NN*32*2;   // 6.4MB
  unsigned short* wb1   = (unsigned short*)w;  w += (size_t)CC*32*2;
  unsigned short* wrb   = (unsigned short*)w;  w += (size_t)CC*32*2;

  const int EB = (EE + 255)/256;
  const int NBK = (NN + 255)/256;

  // CSR + graph-boundary build + weight/input converts
  k_init0<<<NBK,256,0,stream>>>(deg);
  k_count<<<EB,256,0,stream>>>(dst, deg);
  k_scan_local<<<NB,256,0,stream>>>(deg, rowptr, bsum);
  k_scan_bsums<<<1,64,0,stream>>>(bsum, rowptr);
  k_scan_add<<<NB,256,0,stream>>>(rowptr, bsum, cursor);
  k_scatter<<<EB,256,0,stream>>>(src, dst, cursor, csr);
  k_graph_ptr<<<NBK,256,0,stream>>>(gid, gptr);
  k_cvtw2<<<(CC*CC+255)/256,256,0,stream>>>(fc2w, wb2);
  k_cvtx<<<(NN*32+255)/256,256,0,stream>>>(x, xb);
  k_cvtw1<<<(CC*32+255)/256,256,0,stream>>>(fc1w, res1w, wb1, wrb);

  // layer 1 (MFMA)
  k_feat1m<<<1024,256,0,stream>>>(xb, wb1, wrb, b1, al1, ar1, featb, resb, el, er);
  k_aggr1<<<(NN+7)/8,256,0,stream>>>(rowptr, csr, el, er, featb, resb, hb);
  // layer 2
  k_feat2<<<(NN/16*2+3)/4,256,0,stream>>>(hb, wb2, al2, ar2, featb, el, er);
  // fused aggregation + readout + gnn_last + LayerNorm (block per graph)
  k_aggr2<<<GG,256,0,stream>>>(gptr, rowptr, csr, el, er, featb, hb,
                               b2, aww, awb, outw, outb, out);
}

// Round 12
// 210.399 us; speedup vs baseline: 9.6367x; 1.0227x over previous
//
#include <hip/hip_runtime.h>
#include <math.h>

#define NN 100000
#define EE 400000
#define GG 4096
#define INF_ 27
#define CC 128   // H*D
#define HH 4
#define DD 32
#define NB 98    // ceil(NN/1024) scan blocks

typedef short bf16x8 __attribute__((ext_vector_type(8)));
typedef float f32x4 __attribute__((ext_vector_type(4)));

// ---- bf16 helpers (RNE) ----
static __device__ __forceinline__ unsigned short f2bf(float f){
  unsigned u = __float_as_uint(f);
  u += 0x7fffu + ((u>>16)&1u);
  return (unsigned short)(u>>16);
}
static __device__ __forceinline__ float bf2f(unsigned short s){
  return __uint_as_float(((unsigned)s)<<16);
}

// ---- fused prep: zero deg, graph boundaries, x->bf16(pad32), w1/res1/w2->bf16 ----
__global__ __launch_bounds__(256) void k_prep(
    const float* __restrict__ x, const float* __restrict__ fcw,
    const float* __restrict__ resw, const float* __restrict__ w2,
    const int* __restrict__ gid,
    unsigned short* __restrict__ xb, unsigned short* __restrict__ wb1,
    unsigned short* __restrict__ wrb, unsigned short* __restrict__ wb2,
    int* __restrict__ deg, int* __restrict__ gptr)
{
  int i = blockIdx.x*256 + threadIdx.x;
  if (i < NN*32){
    int n = i>>5, k = i&31;
    xb[i] = (k<INF_) ? f2bf(x[n*INF_+k]) : (unsigned short)0;
  }
  if (i < NN){
    deg[i] = 0;
    int g = gid[i];
    int gp = (i==0) ? -1 : gid[i-1];
    for (int q=gp+1; q<=g; q++) gptr[q] = i;
    if (i==NN-1){
      for (int q=g+1; q<=GG; q++) gptr[q] = NN;
    }
  }
  if (i < CC*CC) wb2[i] = f2bf(w2[i]);
  if (i < CC*32){
    int c = i>>5, k = i&31;
    wb1[i] = (k<INF_) ? f2bf(fcw[c*INF_+k]) : (unsigned short)0;
    wrb[i] = (k<INF_) ? f2bf(resw[c*INF_+k]) : (unsigned short)0;
  }
}

__global__ void k_count(const int* __restrict__ dst, int* __restrict__ deg){
  int i = blockIdx.x*blockDim.x + threadIdx.x;
  if (i < EE) atomicAdd(&deg[dst[i]], 1);
}

__global__ __launch_bounds__(256) void k_scan_local(const int* __restrict__ deg,
                                                    int* __restrict__ rowptr,
                                                    int* __restrict__ bsum){
  __shared__ int sh[256];
  int t = threadIdx.x;
  int idx = blockIdx.x*1024 + t*4;
  int v0 = (idx+0<NN)?deg[idx+0]:0;
  int v1 = (idx+1<NN)?deg[idx+1]:0;
  int v2 = (idx+2<NN)?deg[idx+2]:0;
  int v3 = (idx+3<NN)?deg[idx+3]:0;
  sh[t] = v0+v1+v2+v3;
  __syncthreads();
  for (int o=1;o<256;o<<=1){
    int x = (t>=o)? sh[t-o] : 0;
    __syncthreads();
    sh[t] += x;
    __syncthreads();
  }
  int run = (t==0)? 0 : sh[t-1];
  if (t==255) bsum[blockIdx.x] = sh[255];
  if (idx+0<NN){ rowptr[idx+0]=run; run+=v0; }
  if (idx+1<NN){ rowptr[idx+1]=run; run+=v1; }
  if (idx+2<NN){ rowptr[idx+2]=run; run+=v2; }
  if (idx+3<NN){ rowptr[idx+3]=run; }
}

__global__ void k_scan_bsums(int* __restrict__ bsum, int* __restrict__ rowptr){
  if (threadIdx.x==0 && blockIdx.x==0){
    int run = 0;
    for (int b=0;b<NB;b++){ int v=bsum[b]; bsum[b]=run; run+=v; }
    rowptr[NN] = run;
  }
}

__global__ __launch_bounds__(256) void k_scan_add(int* __restrict__ rowptr,
                                                  const int* __restrict__ bsum,
                                                  int* __restrict__ cursor){
  int idx = blockIdx.x*1024 + threadIdx.x*4;
  int off = bsum[blockIdx.x];
  #pragma unroll
  for (int i=0;i<4;i++){
    if (idx+i<NN){ int r = rowptr[idx+i]+off; rowptr[idx+i]=r; cursor[idx+i]=r; }
  }
}

__global__ void k_scatter(const int* __restrict__ src, const int* __restrict__ dst,
                          int* __restrict__ cursor, int* __restrict__ csr_src){
  int i = blockIdx.x*blockDim.x + threadIdx.x;
  if (i < EE){
    int pos = atomicAdd(&cursor[dst[i]], 1);
    csr_src[pos] = src[i];
  }
}

// ---- layer1 via MFMA: featb = bf16(x@fc1^T), resb = bf16(x@res1^T + b1), el/er ----
__global__ __launch_bounds__(256) void k_feat1m(
    const unsigned short* __restrict__ xb, const unsigned short* __restrict__ wb1,
    const unsigned short* __restrict__ wrb, const float* __restrict__ bias,
    const float* __restrict__ al, const float* __restrict__ ar,
    unsigned short* __restrict__ featb, unsigned short* __restrict__ resb,
    float* __restrict__ el, float* __restrict__ er)
{
  int wid = (blockIdx.x*256 + threadIdx.x) >> 6;
  int lane = threadIdx.x & 63;
  int l15 = lane & 15, khi = lane >> 4;
  int nw = gridDim.x*4;
  bf16x8 wf[8], wr[8];
  float bv8[8];
  #pragma unroll
  for (int ct=0; ct<8; ct++){
    wf[ct] = *(const bf16x8*)(wb1 + (ct*16+l15)*32 + khi*8);
    wr[ct] = *(const bf16x8*)(wrb + (ct*16+l15)*32 + khi*8);
    bv8[ct] = bias[ct*16+l15];
  }
  float a0v[4], a1v[4], b0v[4], b1v[4];
  #pragma unroll
  for (int hh=0; hh<4; hh++){
    int c0 = hh*32 + l15;
    a0v[hh] = al[c0]; a1v[hh] = al[c0+16];
    b0v[hh] = ar[c0]; b1v[hh] = ar[c0+16];
  }
  for (int tile = wid; tile < NN/16; tile += nw){
    int n0 = tile*16;
    bf16x8 af = *(const bf16x8*)(xb + (size_t)(n0+l15)*32 + khi*8);
    f32x4 accf[8], accr[8];
    #pragma unroll
    for (int ct=0; ct<8; ct++){
      accf[ct] = __builtin_amdgcn_mfma_f32_16x16x32_bf16(af, wf[ct], (f32x4){0.f,0.f,0.f,0.f}, 0,0,0);
      accr[ct] = __builtin_amdgcn_mfma_f32_16x16x32_bf16(af, wr[ct], (f32x4){0.f,0.f,0.f,0.f}, 0,0,0);
    }
    #pragma unroll
    for (int ct=0; ct<8; ct++){
      int c = ct*16+l15;
      #pragma unroll
      for (int r=0;r<4;r++){
        int n = n0 + khi*4 + r;
        featb[(size_t)n*CC + c] = f2bf(accf[ct][r]);
        resb [(size_t)n*CC + c] = f2bf(accr[ct][r] + bv8[ct]);
      }
    }
    #pragma unroll
    for (int hh=0; hh<4; hh++){
      #pragma unroll
      for (int r=0;r<4;r++){
        float pe = accf[2*hh][r]*a0v[hh] + accf[2*hh+1][r]*a1v[hh];
        float pr = accf[2*hh][r]*b0v[hh] + accf[2*hh+1][r]*b1v[hh];
        #pragma unroll
        for (int o=8;o;o>>=1){ pe += __shfl_xor(pe,o,16); pr += __shfl_xor(pr,o,16); }
        if (l15==0){
          int n = n0 + khi*4 + r;
          el[n*HH + hh] = pe;
          er[n*HH + hh] = pr;
        }
      }
    }
  }
}

// ---- layer2 GEMM via MFMA: featb = bf16(hb @ fc2^T), el/er dots ----
__global__ __launch_bounds__(256) void k_feat2(
    const unsigned short* __restrict__ hb, const unsigned short* __restrict__ wb2,
    const float* __restrict__ al, const float* __restrict__ ar,
    unsigned short* __restrict__ featb, float* __restrict__ el, float* __restrict__ er)
{
  int wid = (blockIdx.x*256 + threadIdx.x) >> 6;
  int lane = threadIdx.x & 63;
  int tile = wid >> 1;
  int ch = wid & 1;
  if (tile >= NN/16) return;
  int l15 = lane & 15, khi = lane >> 4;
  int n0 = tile*16;
  bf16x8 wf[4][4];
  #pragma unroll
  for (int ct=0; ct<4; ct++)
    #pragma unroll
    for (int ks=0; ks<4; ks++)
      wf[ct][ks] = *(const bf16x8*)(wb2 + (size_t)(ch*64+ct*16+l15)*CC + ks*32 + khi*8);
  bf16x8 af[4];
  #pragma unroll
  for (int ks=0; ks<4; ks++)
    af[ks] = *(const bf16x8*)(hb + (size_t)(n0+l15)*CC + ks*32 + khi*8);
  f32x4 accf[4] = {{0.f,0.f,0.f,0.f},{0.f,0.f,0.f,0.f},{0.f,0.f,0.f,0.f},{0.f,0.f,0.f,0.f}};
  #pragma unroll
  for (int ks=0; ks<4; ks++)
    #pragma unroll
    for (int ct=0; ct<4; ct++)
      accf[ct] = __builtin_amdgcn_mfma_f32_16x16x32_bf16(af[ks], wf[ct][ks], accf[ct], 0,0,0);
  #pragma unroll
  for (int ct=0; ct<4; ct++)
    #pragma unroll
    for (int r=0;r<4;r++)
      featb[(size_t)(n0+khi*4+r)*CC + ch*64+ct*16+l15] = f2bf(accf[ct][r]);
  #pragma unroll
  for (int hh=0; hh<2; hh++){
    int c0 = ch*64 + hh*32 + l15;
    float a0 = al[c0], a1 = al[c0+16], b0 = ar[c0], b1 = ar[c0+16];
    #pragma unroll
    for (int r=0;r<4;r++){
      float pe = accf[2*hh][r]*a0 + accf[2*hh+1][r]*a1;
      float pr = accf[2*hh][r]*b0 + accf[2*hh+1][r]*b1;
      #pragma unroll
      for (int o=8;o;o>>=1){ pe += __shfl_xor(pe,o,16); pr += __shfl_xor(pr,o,16); }
      if (l15==0){
        int n = n0 + khi*4 + r;
        el[n*HH + ch*2+hh] = pe;
        er[n*HH + ch*2+hh] = pr;
      }
    }
  }
}

// ---- layer1 aggregation: single-pass softmax, 4-edge unroll for MLP,
//      epilogue elu(res + rst) -> hb(bf16). half-wave per node. ----
__global__ __launch_bounds__(256) void k_aggr1(
    const int* __restrict__ rowptr, const int* __restrict__ csr,
    const float* __restrict__ el, const float* __restrict__ er,
    const unsigned short* __restrict__ featb,
    const unsigned short* __restrict__ resb,
    unsigned short* __restrict__ hb)
{
  int t = threadIdx.x;
  int n = blockIdx.x*8 + (t>>5);
  if (n >= NN) return;
  int lane = t & 31;
  int h = lane >> 3;
  int e0 = rowptr[n], e1 = rowptr[n+1];
  float ern = er[n*HH + h];
  float ssum = 0.f;
  float r0=0.f,r1=0.f,r2=0.f,r3=0.f;
  int j = e0;
  for (; j+4 <= e1; j += 4){
    int sA = csr[j], sB = csr[j+1], sC = csr[j+2], sD = csr[j+3];
    float vA = el[sA*HH+h] + ern; vA = vA>0.f?vA:0.2f*vA;
    float vB = el[sB*HH+h] + ern; vB = vB>0.f?vB:0.2f*vB;
    float vC = el[sC*HH+h] + ern; vC = vC>0.f?vC:0.2f*vC;
    float vD = el[sD*HH+h] + ern; vD = vD>0.f?vD:0.2f*vD;
    float aA = __expf(vA), aB = __expf(vB), aC = __expf(vC), aD = __expf(vD);
    ssum += (aA + aB) + (aC + aD);
    ushort4 fA = *(const ushort4*)(featb + (size_t)sA*CC + lane*4);
    ushort4 fB = *(const ushort4*)(featb + (size_t)sB*CC + lane*4);
    ushort4 fC = *(const ushort4*)(featb + (size_t)sC*CC + lane*4);
    ushort4 fD = *(const ushort4*)(featb + (size_t)sD*CC + lane*4);
    r0 = fmaf(bf2f(fA.x), aA, r0); r1 = fmaf(bf2f(fA.y), aA, r1);
    r2 = fmaf(bf2f(fA.z), aA, r2); r3 = fmaf(bf2f(fA.w), aA, r3);
    r0 = fmaf(bf2f(fB.x), aB, r0); r1 = fmaf(bf2f(fB.y), aB, r1);
    r2 = fmaf(bf2f(fB.z), aB, r2); r3 = fmaf(bf2f(fB.w), aB, r3);
    r0 = fmaf(bf2f(fC.x), aC, r0); r1 = fmaf(bf2f(fC.y), aC, r1);
    r2 = fmaf(bf2f(fC.z), aC, r2); r3 = fmaf(bf2f(fC.w), aC, r3);
    r0 = fmaf(bf2f(fD.x), aD, r0); r1 = fmaf(bf2f(fD.y), aD, r1);
    r2 = fmaf(bf2f(fD.z), aD, r2); r3 = fmaf(bf2f(fD.w), aD, r3);
  }
  for (; j < e1; j++){
    int sA = csr[j];
    float vA = el[sA*HH+h] + ern; vA = vA>0.f?vA:0.2f*vA;
    float aA = __expf(vA);
    ssum += aA;
    ushort4 fA = *(const ushort4*)(featb + (size_t)sA*CC + lane*4);
    r0 = fmaf(bf2f(fA.x), aA, r0); r1 = fmaf(bf2f(fA.y), aA, r1);
    r2 = fmaf(bf2f(fA.z), aA, r2); r3 = fmaf(bf2f(fA.w), aA, r3);
  }
  float inv = (e1 > e0) ? 1.f/ssum : 0.f;
  ushort4 rv = *(const ushort4*)(resb + (size_t)n*CC + lane*4);
  float t0 = bf2f(rv.x) + r0*inv;
  float t1 = bf2f(rv.y) + r1*inv;
  float t2 = bf2f(rv.z) + r2*inv;
  float t3 = bf2f(rv.w) + r3*inv;
  t0 = t0 > 0.f ? t0 : __expf(t0)-1.f;
  t1 = t1 > 0.f ? t1 : __expf(t1)-1.f;
  t2 = t2 > 0.f ? t2 : __expf(t2)-1.f;
  t3 = t3 > 0.f ? t3 : __expf(t3)-1.f;
  ushort4 hb4; hb4.x=f2bf(t0); hb4.y=f2bf(t1); hb4.z=f2bf(t2); hb4.w=f2bf(t3);
  *(ushort4*)(hb + (size_t)n*CC + lane*4) = hb4;
}

// ---- layer2 aggregation + readout + output: ONE BLOCK PER GRAPH, 4-edge unroll ----
__global__ __launch_bounds__(256) void k_aggr2(
    const int* __restrict__ gptr, const int* __restrict__ rowptr,
    const int* __restrict__ csr,
    const float* __restrict__ el, const float* __restrict__ er,
    const unsigned short* __restrict__ featb,
    const unsigned short* __restrict__ hb,
    const float* __restrict__ b2, const float* __restrict__ aww,
    const float* __restrict__ awb,
    const float* __restrict__ outw, const float* __restrict__ outb,
    float* __restrict__ out)
{
  __shared__ float lsum[8][32];
  __shared__ float lmax[8][32];
  __shared__ float gv[64];
  __shared__ float rr1[2], rr2[2];
  int g = blockIdx.x;
  int n0 = gptr[g], n1 = gptr[g+1];
  int t = threadIdx.x;
  int grp = t>>5, lane = t&31, h = lane>>3;
  float gs0=0.f,gs1=0.f,gs2=0.f,gs3=0.f;
  float gm0=-3.4e38f,gm1=-3.4e38f,gm2=-3.4e38f,gm3=-3.4e38f;
  float4 bv  = *(const float4*)(b2 + lane*4);
  float4 aw4 = *(const float4*)(aww + (lane&7)*4);
  float awbv = awb[0];
  for (int n = n0+grp; n < n1; n += 8){
    int e0 = rowptr[n], e1 = rowptr[n+1];
    float ern = er[n*HH + h];
    float ssum = 0.f;
    float r0=0.f,r1=0.f,r2=0.f,r3=0.f;
    int j = e0;
    for (; j+4 <= e1; j += 4){
      int sA = csr[j], sB = csr[j+1], sC = csr[j+2], sD = csr[j+3];
      float vA = el[sA*HH+h] + ern; vA = vA>0.f?vA:0.2f*vA;
      float vB = el[sB*HH+h] + ern; vB = vB>0.f?vB:0.2f*vB;
      float vC = el[sC*HH+h] + ern; vC = vC>0.f?vC:0.2f*vC;
      float vD = el[sD*HH+h] + ern; vD = vD>0.f?vD:0.2f*vD;
      float aA = __expf(vA), aB = __expf(vB), aC = __expf(vC), aD = __expf(vD);
      ssum += (aA + aB) + (aC + aD);
      ushort4 fA = *(const ushort4*)(featb + (size_t)sA*CC + lane*4);
      ushort4 fB = *(const ushort4*)(featb + (size_t)sB*CC + lane*4);
      ushort4 fC = *(const ushort4*)(featb + (size_t)sC*CC + lane*4);
      ushort4 fD = *(const ushort4*)(featb + (size_t)sD*CC + lane*4);
      r0 = fmaf(bf2f(fA.x), aA, r0); r1 = fmaf(bf2f(fA.y), aA, r1);
      r2 = fmaf(bf2f(fA.z), aA, r2); r3 = fmaf(bf2f(fA.w), aA, r3);
      r0 = fmaf(bf2f(fB.x), aB, r0); r1 = fmaf(bf2f(fB.y), aB, r1);
      r2 = fmaf(bf2f(fB.z), aB, r2); r3 = fmaf(bf2f(fB.w), aB, r3);
      r0 = fmaf(bf2f(fC.x), aC, r0); r1 = fmaf(bf2f(fC.y), aC, r1);
      r2 = fmaf(bf2f(fC.z), aC, r2); r3 = fmaf(bf2f(fC.w), aC, r3);
      r0 = fmaf(bf2f(fD.x), aD, r0); r1 = fmaf(bf2f(fD.y), aD, r1);
      r2 = fmaf(bf2f(fD.z), aD, r2); r3 = fmaf(bf2f(fD.w), aD, r3);
    }
    for (; j < e1; j++){
      int sA = csr[j];
      float vA = el[sA*HH+h] + ern; vA = vA>0.f?vA:0.2f*vA;
      float aA = __expf(vA);
      ssum += aA;
      ushort4 fA = *(const ushort4*)(featb + (size_t)sA*CC + lane*4);
      r0 = fmaf(bf2f(fA.x), aA, r0); r1 = fmaf(bf2f(fA.y), aA, r1);
      r2 = fmaf(bf2f(fA.z), aA, r2); r3 = fmaf(bf2f(fA.w), aA, r3);
    }
    float inv = (e1 > e0) ? 1.f/ssum : 0.f;
    ushort4 hv = *(const ushort4*)(hb + (size_t)n*CC + lane*4);
    float t0 = bf2f(hv.x) + bv.x + r0*inv;
    float t1 = bf2f(hv.y) + bv.y + r1*inv;
    float t2 = bf2f(hv.z) + bv.z + r2*inv;
    float t3 = bf2f(hv.w) + bv.w + r3*inv;
    float s0=t0,s1=t1,s2=t2,s3=t3;
    s0 += __shfl_xor(s0,8,32);  s1 += __shfl_xor(s1,8,32);
    s2 += __shfl_xor(s2,8,32);  s3 += __shfl_xor(s3,8,32);
    s0 += __shfl_xor(s0,16,32); s1 += __shfl_xor(s1,16,32);
    s2 += __shfl_xor(s2,16,32); s3 += __shfl_xor(s3,16,32);
    float hm0=0.25f*s0, hm1=0.25f*s1, hm2=0.25f*s2, hm3=0.25f*s3;
    float p = hm0*aw4.x + hm1*aw4.y + hm2*aw4.z + hm3*aw4.w;
    p += __shfl_xor(p,1,32); p += __shfl_xor(p,2,32); p += __shfl_xor(p,4,32);
    float wgt = 1.f/(1.f + __expf(-(p + awbv)));
    gs0 = fmaf(wgt, hm0, gs0); gs1 = fmaf(wgt, hm1, gs1);
    gs2 = fmaf(wgt, hm2, gs2); gs3 = fmaf(wgt, hm3, gs3);
    gm0 = fmaxf(gm0, hm0); gm1 = fmaxf(gm1, hm1);
    gm2 = fmaxf(gm2, hm2); gm3 = fmaxf(gm3, hm3);
  }
  if (lane < 8){
    int c = lane*4;
    lsum[grp][c+0]=gs0; lsum[grp][c+1]=gs1; lsum[grp][c+2]=gs2; lsum[grp][c+3]=gs3;
    lmax[grp][c+0]=gm0; lmax[grp][c+1]=gm1; lmax[grp][c+2]=gm2; lmax[grp][c+3]=gm3;
  }
  __syncthreads();
  if (t < 32){
    float s=0.f, m=-3.4e38f;
    #pragma unroll
    for (int q=0;q<8;q++){ s += lsum[q][t]; m = fmaxf(m, lmax[q][t]); }
    gv[t]    = s;
    gv[32+t] = (m < -3.0e38f) ? 0.f : m;
  }
  __syncthreads();
  float y = 0.f;
  if (t < 128){
    y = outb[t];
    #pragma unroll
    for (int jj=0;jj<64;jj++) y = fmaf(gv[jj], outw[t*64+jj], y);
    float s1 = y, s2 = y*y;
    #pragma unroll
    for (int o=32;o;o>>=1){ s1 += __shfl_xor(s1,o); s2 += __shfl_xor(s2,o); }
    if ((t&63)==0){ rr1[t>>6]=s1; rr2[t>>6]=s2; }
  }
  __syncthreads();
  if (t < 128){
    float S1 = rr1[0]+rr1[1], S2 = rr2[0]+rr2[1];
    float mu = S1*(1.f/128.f);
    float var = S2*(1.f/128.f) - mu*mu;
    out[g*CC + t] = (y - mu) * rsqrtf(var + 1e-5f);
  }
}

extern "C" void kernel_launch(void* const* d_in, const int* in_sizes, int n_in,
                              void* d_out, int out_size, void* d_ws, size_t ws_size,
                              hipStream_t stream){
  const float* x     = (const float*)d_in[0];
  const int*   src   = (const int*)d_in[1];
  const int*   dst   = (const int*)d_in[2];
  const int*   gid   = (const int*)d_in[3];
  const float* fc1w  = (const float*)d_in[4];
  const float* al1   = (const float*)d_in[5];
  const float* ar1   = (const float*)d_in[6];
  const float* res1w = (const float*)d_in[7];
  const float* b1    = (const float*)d_in[8];
  const float* fc2w  = (const float*)d_in[9];
  const float* al2   = (const float*)d_in[10];
  const float* ar2   = (const float*)d_in[11];
  const float* b2    = (const float*)d_in[12];
  const float* aww   = (const float*)d_in[13];
  const float* awb   = (const float*)d_in[14];
  const float* outw  = (const float*)d_in[15];
  const float* outb  = (const float*)d_in[16];
  float* out = (float*)d_out;

  char* w = (char*)d_ws;
  unsigned short* featb = (unsigned short*)w;  w += (size_t)NN*CC*2;   // 25.6MB
  unsigned short* hb    = (unsigned short*)w;  w += (size_t)NN*CC*2;   // 25.6MB
  unsigned short* resb  = (unsigned short*)w;  w += (size_t)NN*CC*2;   // 25.6MB
  float*          el    = (float*)w;           w += (size_t)NN*HH*4;
  float*          er    = (float*)w;           w += (size_t)NN*HH*4;
  int*            deg   = (int*)w;             w += (size_t)NN*4;
  int*            rowptr= (int*)w;             w += (size_t)(NN+1)*4;
  int*            cursor= (int*)w;             w += (size_t)NN*4;
  int*            bsum  = (int*)w;             w += 128*4;
  int*            csr   = (int*)w;             w += (size_t)EE*4;
  int*            gptr  = (int*)w;             w += (size_t)(GG+1)*4;
  unsigned short* wb2   = (unsigned short*)w;  w += (size_t)CC*CC*2;
  unsigned short* xb    = (unsigned short*)w;  w += (size_t)NN*32*2;   // 6.4MB
  unsigned short* wb1   = (unsigned short*)w;  w += (size_t)CC*32*2;
  unsigned short* wrb   = (unsigned short*)w;  w += (size_t)CC*32*2;

  const int EB = (EE + 255)/256;

  // fused prep (deg zero, gptr, bf16 converts) + CSR build
  k_prep<<<(NN*32+255)/256,256,0,stream>>>(x, fc1w, res1w, fc2w, gid,
                                           xb, wb1, wrb, wb2, deg, gptr);
  k_count<<<EB,256,0,stream>>>(dst, deg);
  k_scan_local<<<NB,256,0,stream>>>(deg, rowptr, bsum);
  k_scan_bsums<<<1,64,0,stream>>>(bsum, rowptr);
  k_scan_add<<<NB,256,0,stream>>>(rowptr, bsum, cursor);
  k_scatter<<<EB,256,0,stream>>>(src, dst, cursor, csr);

  // layer 1 (MFMA)
  k_feat1m<<<1024,256,0,stream>>>(xb, wb1, wrb, b1, al1, ar1, featb, resb, el, er);
  k_aggr1<<<(NN+7)/8,256,0,stream>>>(rowptr, csr, el, er, featb, resb, hb);
  // layer 2
  k_feat2<<<(NN/16*2+3)/4,256,0,stream>>>(hb, wb2, al2, ar2, featb, el, er);
  // fused aggregation + readout + gnn_last + LayerNorm (block per graph)
  k_aggr2<<<GG,256,0,stream>>>(gptr, rowptr, csr, el, er, featb, hb,
                               b2, aww, awb, outw, outb, out);
}

// Round 13
// 201.784 us; speedup vs baseline: 10.0481x; 1.0427x over previous
//
#include <hip/hip_runtime.h>
#include <math.h>

#define NN 100000
#define EE 400000
#define GG 4096
#define INF_ 27
#define CC 128   // H*D
#define HH 4
#define DD 32
#define NB 98    // ceil(NN/1024) scan blocks

typedef short bf16x8 __attribute__((ext_vector_type(8)));
typedef float f32x4 __attribute__((ext_vector_type(4)));

// ---- bf16 helpers (RNE) ----
static __device__ __forceinline__ unsigned short f2bf(float f){
  unsigned u = __float_as_uint(f);
  u += 0x7fffu + ((u>>16)&1u);
  return (unsigned short)(u>>16);
}
static __device__ __forceinline__ float bf2f(unsigned short s){
  return __uint_as_float(((unsigned)s)<<16);
}

// ---- fused prep: zero deg, graph boundaries, x->bf16(pad32), w1/res1/w2->bf16 ----
__global__ __launch_bounds__(256) void k_prep(
    const float* __restrict__ x, const float* __restrict__ fcw,
    const float* __restrict__ resw, const float* __restrict__ w2,
    const int* __restrict__ gid,
    unsigned short* __restrict__ xb, unsigned short* __restrict__ wb1,
    unsigned short* __restrict__ wrb, unsigned short* __restrict__ wb2,
    int* __restrict__ deg, int* __restrict__ gptr)
{
  int i = blockIdx.x*256 + threadIdx.x;
  if (i < NN*32){
    int n = i>>5, k = i&31;
    xb[i] = (k<INF_) ? f2bf(x[n*INF_+k]) : (unsigned short)0;
  }
  if (i < NN){
    deg[i] = 0;
    int g = gid[i];
    int gp = (i==0) ? -1 : gid[i-1];
    for (int q=gp+1; q<=g; q++) gptr[q] = i;
    if (i==NN-1){
      for (int q=g+1; q<=GG; q++) gptr[q] = NN;
    }
  }
  if (i < CC*CC) wb2[i] = f2bf(w2[i]);
  if (i < CC*32){
    int c = i>>5, k = i&31;
    wb1[i] = (k<INF_) ? f2bf(fcw[c*INF_+k]) : (unsigned short)0;
    wrb[i] = (k<INF_) ? f2bf(resw[c*INF_+k]) : (unsigned short)0;
  }
}

__global__ void k_count(const int* __restrict__ dst, int* __restrict__ deg){
  int i = blockIdx.x*blockDim.x + threadIdx.x;
  if (i < EE) atomicAdd(&deg[dst[i]], 1);
}

__global__ __launch_bounds__(256) void k_scan_local(const int* __restrict__ deg,
                                                    int* __restrict__ rowptr,
                                                    int* __restrict__ bsum){
  __shared__ int sh[256];
  int t = threadIdx.x;
  int idx = blockIdx.x*1024 + t*4;
  int v0 = (idx+0<NN)?deg[idx+0]:0;
  int v1 = (idx+1<NN)?deg[idx+1]:0;
  int v2 = (idx+2<NN)?deg[idx+2]:0;
  int v3 = (idx+3<NN)?deg[idx+3]:0;
  sh[t] = v0+v1+v2+v3;
  __syncthreads();
  for (int o=1;o<256;o<<=1){
    int x = (t>=o)? sh[t-o] : 0;
    __syncthreads();
    sh[t] += x;
    __syncthreads();
  }
  int run = (t==0)? 0 : sh[t-1];
  if (t==255) bsum[blockIdx.x] = sh[255];
  if (idx+0<NN){ rowptr[idx+0]=run; run+=v0; }
  if (idx+1<NN){ rowptr[idx+1]=run; run+=v1; }
  if (idx+2<NN){ rowptr[idx+2]=run; run+=v2; }
  if (idx+3<NN){ rowptr[idx+3]=run; }
}

__global__ void k_scan_bsums(int* __restrict__ bsum, int* __restrict__ rowptr){
  if (threadIdx.x==0 && blockIdx.x==0){
    int run = 0;
    for (int b=0;b<NB;b++){ int v=bsum[b]; bsum[b]=run; run+=v; }
    rowptr[NN] = run;
  }
}

__global__ __launch_bounds__(256) void k_scan_add(int* __restrict__ rowptr,
                                                  const int* __restrict__ bsum,
                                                  int* __restrict__ cursor){
  int idx = blockIdx.x*1024 + threadIdx.x*4;
  int off = bsum[blockIdx.x];
  #pragma unroll
  for (int i=0;i<4;i++){
    if (idx+i<NN){ int r = rowptr[idx+i]+off; rowptr[idx+i]=r; cursor[idx+i]=r; }
  }
}

__global__ void k_scatter(const int* __restrict__ src, const int* __restrict__ dst,
                          int* __restrict__ cursor, int* __restrict__ csr_src){
  int i = blockIdx.x*blockDim.x + threadIdx.x;
  if (i < EE){
    int pos = atomicAdd(&cursor[dst[i]], 1);
    csr_src[pos] = src[i];
  }
}

// ---- layer1 via MFMA: featb = bf16(x@fc1^T), resb = bf16(x@res1^T + b1), el/er ----
__global__ __launch_bounds__(256) void k_feat1m(
    const unsigned short* __restrict__ xb, const unsigned short* __restrict__ wb1,
    const unsigned short* __restrict__ wrb, const float* __restrict__ bias,
    const float* __restrict__ al, const float* __restrict__ ar,
    unsigned short* __restrict__ featb, unsigned short* __restrict__ resb,
    float* __restrict__ el, float* __restrict__ er)
{
  int wid = (blockIdx.x*256 + threadIdx.x) >> 6;
  int lane = threadIdx.x & 63;
  int l15 = lane & 15, khi = lane >> 4;
  int nw = gridDim.x*4;
  bf16x8 wf[8], wr[8];
  float bv8[8];
  #pragma unroll
  for (int ct=0; ct<8; ct++){
    wf[ct] = *(const bf16x8*)(wb1 + (ct*16+l15)*32 + khi*8);
    wr[ct] = *(const bf16x8*)(wrb + (ct*16+l15)*32 + khi*8);
    bv8[ct] = bias[ct*16+l15];
  }
  float a0v[4], a1v[4], b0v[4], b1v[4];
  #pragma unroll
  for (int hh=0; hh<4; hh++){
    int c0 = hh*32 + l15;
    a0v[hh] = al[c0]; a1v[hh] = al[c0+16];
    b0v[hh] = ar[c0]; b1v[hh] = ar[c0+16];
  }
  for (int tile = wid; tile < NN/16; tile += nw){
    int n0 = tile*16;
    bf16x8 af = *(const bf16x8*)(xb + (size_t)(n0+l15)*32 + khi*8);
    f32x4 accf[8], accr[8];
    #pragma unroll
    for (int ct=0; ct<8; ct++){
      accf[ct] = __builtin_amdgcn_mfma_f32_16x16x32_bf16(af, wf[ct], (f32x4){0.f,0.f,0.f,0.f}, 0,0,0);
      accr[ct] = __builtin_amdgcn_mfma_f32_16x16x32_bf16(af, wr[ct], (f32x4){0.f,0.f,0.f,0.f}, 0,0,0);
    }
    #pragma unroll
    for (int ct=0; ct<8; ct++){
      int c = ct*16+l15;
      #pragma unroll
      for (int r=0;r<4;r++){
        int n = n0 + khi*4 + r;
        featb[(size_t)n*CC + c] = f2bf(accf[ct][r]);
        resb [(size_t)n*CC + c] = f2bf(accr[ct][r] + bv8[ct]);
      }
    }
    #pragma unroll
    for (int hh=0; hh<4; hh++){
      #pragma unroll
      for (int r=0;r<4;r++){
        float pe = accf[2*hh][r]*a0v[hh] + accf[2*hh+1][r]*a1v[hh];
        float pr = accf[2*hh][r]*b0v[hh] + accf[2*hh+1][r]*b1v[hh];
        #pragma unroll
        for (int o=8;o;o>>=1){ pe += __shfl_xor(pe,o,16); pr += __shfl_xor(pr,o,16); }
        if (l15==0){
          int n = n0 + khi*4 + r;
          el[n*HH + hh] = pe;
          er[n*HH + hh] = pr;
        }
      }
    }
  }
}

// ---- layer2 GEMM via MFMA: featb = bf16(hb @ fc2^T), el/er dots ----
__global__ __launch_bounds__(256) void k_feat2(
    const unsigned short* __restrict__ hb, const unsigned short* __restrict__ wb2,
    const float* __restrict__ al, const float* __restrict__ ar,
    unsigned short* __restrict__ featb, float* __restrict__ el, float* __restrict__ er)
{
  int wid = (blockIdx.x*256 + threadIdx.x) >> 6;
  int lane = threadIdx.x & 63;
  int tile = wid >> 1;
  int ch = wid & 1;
  if (tile >= NN/16) return;
  int l15 = lane & 15, khi = lane >> 4;
  int n0 = tile*16;
  bf16x8 wf[4][4];
  #pragma unroll
  for (int ct=0; ct<4; ct++)
    #pragma unroll
    for (int ks=0; ks<4; ks++)
      wf[ct][ks] = *(const bf16x8*)(wb2 + (size_t)(ch*64+ct*16+l15)*CC + ks*32 + khi*8);
  bf16x8 af[4];
  #pragma unroll
  for (int ks=0; ks<4; ks++)
    af[ks] = *(const bf16x8*)(hb + (size_t)(n0+l15)*CC + ks*32 + khi*8);
  f32x4 accf[4] = {{0.f,0.f,0.f,0.f},{0.f,0.f,0.f,0.f},{0.f,0.f,0.f,0.f},{0.f,0.f,0.f,0.f}};
  #pragma unroll
  for (int ks=0; ks<4; ks++)
    #pragma unroll
    for (int ct=0; ct<4; ct++)
      accf[ct] = __builtin_amdgcn_mfma_f32_16x16x32_bf16(af[ks], wf[ct][ks], accf[ct], 0,0,0);
  #pragma unroll
  for (int ct=0; ct<4; ct++)
    #pragma unroll
    for (int r=0;r<4;r++)
      featb[(size_t)(n0+khi*4+r)*CC + ch*64+ct*16+l15] = f2bf(accf[ct][r]);
  #pragma unroll
  for (int hh=0; hh<2; hh++){
    int c0 = ch*64 + hh*32 + l15;
    float a0 = al[c0], a1 = al[c0+16], b0 = ar[c0], b1 = ar[c0+16];
    #pragma unroll
    for (int r=0;r<4;r++){
      float pe = accf[2*hh][r]*a0 + accf[2*hh+1][r]*a1;
      float pr = accf[2*hh][r]*b0 + accf[2*hh+1][r]*b1;
      #pragma unroll
      for (int o=8;o;o>>=1){ pe += __shfl_xor(pe,o,16); pr += __shfl_xor(pr,o,16); }
      if (l15==0){
        int n = n0 + khi*4 + r;
        el[n*HH + ch*2+hh] = pe;
        er[n*HH + ch*2+hh] = pr;
      }
    }
  }
}

// ---- layer1 aggregation: 16 lanes/node, 8 channels/lane (bf16x8 loads).
//      single-pass softmax; epilogue elu(res + rst) -> hb(bf16). ----
__global__ __launch_bounds__(256) void k_aggr1(
    const int* __restrict__ rowptr, const int* __restrict__ csr,
    const float* __restrict__ el, const float* __restrict__ er,
    const unsigned short* __restrict__ featb,
    const unsigned short* __restrict__ resb,
    unsigned short* __restrict__ hb)
{
  int t = threadIdx.x;
  int n = blockIdx.x*16 + (t>>4);
  if (n >= NN) return;
  int l = t & 15;
  int h = l >> 2;
  int e0 = rowptr[n], e1 = rowptr[n+1];
  float ern = er[n*HH + h];
  float ssum = 0.f;
  float r[8] = {0.f,0.f,0.f,0.f,0.f,0.f,0.f,0.f};
  int j = e0;
  for (; j+2 <= e1; j += 2){
    int sA = csr[j], sB = csr[j+1];
    float vA = el[sA*HH+h] + ern; vA = vA>0.f?vA:0.2f*vA;
    float vB = el[sB*HH+h] + ern; vB = vB>0.f?vB:0.2f*vB;
    float aA = __expf(vA), aB = __expf(vB);
    ssum += aA + aB;
    bf16x8 fA = *(const bf16x8*)(featb + (size_t)sA*CC + l*8);
    bf16x8 fB = *(const bf16x8*)(featb + (size_t)sB*CC + l*8);
    #pragma unroll
    for (int i=0;i<8;i++){
      r[i] = fmaf(bf2f((unsigned short)fA[i]), aA, r[i]);
      r[i] = fmaf(bf2f((unsigned short)fB[i]), aB, r[i]);
    }
  }
  if (j < e1){
    int sA = csr[j];
    float vA = el[sA*HH+h] + ern; vA = vA>0.f?vA:0.2f*vA;
    float aA = __expf(vA);
    ssum += aA;
    bf16x8 fA = *(const bf16x8*)(featb + (size_t)sA*CC + l*8);
    #pragma unroll
    for (int i=0;i<8;i++) r[i] = fmaf(bf2f((unsigned short)fA[i]), aA, r[i]);
  }
  float inv = (e1 > e0) ? 1.f/ssum : 0.f;
  bf16x8 rv = *(const bf16x8*)(resb + (size_t)n*CC + l*8);
  bf16x8 hb8;
  #pragma unroll
  for (int i=0;i<8;i++){
    float v = bf2f((unsigned short)rv[i]) + r[i]*inv;
    v = v > 0.f ? v : __expf(v)-1.f;
    hb8[i] = (short)f2bf(v);
  }
  *(bf16x8*)(hb + (size_t)n*CC + l*8) = hb8;
}

// ---- layer2 aggregation + readout + output: ONE BLOCK PER GRAPH,
//      16 lanes/node (8 ch/lane), graph sum/max in regs + LDS combine ----
__global__ __launch_bounds__(256) void k_aggr2(
    const int* __restrict__ gptr, const int* __restrict__ rowptr,
    const int* __restrict__ csr,
    const float* __restrict__ el, const float* __restrict__ er,
    const unsigned short* __restrict__ featb,
    const unsigned short* __restrict__ hb,
    const float* __restrict__ b2, const float* __restrict__ aww,
    const float* __restrict__ awb,
    const float* __restrict__ outw, const float* __restrict__ outb,
    float* __restrict__ out)
{
  __shared__ float lsum[16][32];
  __shared__ float lmax[16][32];
  __shared__ float gv[64];
  __shared__ float rr1[2], rr2[2];
  int g = blockIdx.x;
  int n0 = gptr[g], n1 = gptr[g+1];
  int t = threadIdx.x;
  int grp = t>>4, l = t&15, h = l>>2;
  float gs[8] = {0.f,0.f,0.f,0.f,0.f,0.f,0.f,0.f};
  float gm[8] = {-3.4e38f,-3.4e38f,-3.4e38f,-3.4e38f,-3.4e38f,-3.4e38f,-3.4e38f,-3.4e38f};
  float bvv[8], awv[8];
  #pragma unroll
  for (int i=0;i<8;i++){
    bvv[i] = b2[l*8+i];
    awv[i] = aww[(l&3)*8+i];
  }
  float awbv = awb[0];
  for (int n = n0+grp; n < n1; n += 16){
    int e0 = rowptr[n], e1 = rowptr[n+1];
    float ern = er[n*HH + h];
    float ssum = 0.f;
    float r[8] = {0.f,0.f,0.f,0.f,0.f,0.f,0.f,0.f};
    int j = e0;
    for (; j+2 <= e1; j += 2){
      int sA = csr[j], sB = csr[j+1];
      float vA = el[sA*HH+h] + ern; vA = vA>0.f?vA:0.2f*vA;
      float vB = el[sB*HH+h] + ern; vB = vB>0.f?vB:0.2f*vB;
      float aA = __expf(vA), aB = __expf(vB);
      ssum += aA + aB;
      bf16x8 fA = *(const bf16x8*)(featb + (size_t)sA*CC + l*8);
      bf16x8 fB = *(const bf16x8*)(featb + (size_t)sB*CC + l*8);
      #pragma unroll
      for (int i=0;i<8;i++){
        r[i] = fmaf(bf2f((unsigned short)fA[i]), aA, r[i]);
        r[i] = fmaf(bf2f((unsigned short)fB[i]), aB, r[i]);
      }
    }
    if (j < e1){
      int sA = csr[j];
      float vA = el[sA*HH+h] + ern; vA = vA>0.f?vA:0.2f*vA;
      float aA = __expf(vA);
      ssum += aA;
      bf16x8 fA = *(const bf16x8*)(featb + (size_t)sA*CC + l*8);
      #pragma unroll
      for (int i=0;i<8;i++) r[i] = fmaf(bf2f((unsigned short)fA[i]), aA, r[i]);
    }
    float inv = (e1 > e0) ? 1.f/ssum : 0.f;
    bf16x8 hv = *(const bf16x8*)(hb + (size_t)n*CC + l*8);
    float p = 0.f;
    float hm[8];
    #pragma unroll
    for (int i=0;i<8;i++){
      float v = bf2f((unsigned short)hv[i]) + bvv[i] + r[i]*inv;
      // head-sum across the 4 head groups (lanes differing in bits 2-3)
      v += __shfl_xor(v, 4, 16);
      v += __shfl_xor(v, 8, 16);
      hm[i] = 0.25f*v;
      p = fmaf(hm[i], awv[i], p);
    }
    // full gate dot: sum across lane bits 0-1 (d-slices)
    p += __shfl_xor(p, 1, 16);
    p += __shfl_xor(p, 2, 16);
    float wgt = 1.f/(1.f + __expf(-(p + awbv)));
    #pragma unroll
    for (int i=0;i<8;i++){
      gs[i] = fmaf(wgt, hm[i], gs[i]);
      gm[i] = fmaxf(gm[i], hm[i]);
    }
  }
  if (l < 4){
    #pragma unroll
    for (int i=0;i<8;i++){
      lsum[grp][l*8+i] = gs[i];
      lmax[grp][l*8+i] = gm[i];
    }
  }
  __syncthreads();
  if (t < 32){
    float s=0.f, m=-3.4e38f;
    #pragma unroll
    for (int q=0;q<16;q++){ s += lsum[q][t]; m = fmaxf(m, lmax[q][t]); }
    gv[t]    = s;
    gv[32+t] = (m < -3.0e38f) ? 0.f : m;
  }
  __syncthreads();
  float y = 0.f;
  if (t < 128){
    y = outb[t];
    #pragma unroll
    for (int jj=0;jj<64;jj++) y = fmaf(gv[jj], outw[t*64+jj], y);
    float s1 = y, s2 = y*y;
    #pragma unroll
    for (int o=32;o;o>>=1){ s1 += __shfl_xor(s1,o); s2 += __shfl_xor(s2,o); }
    if ((t&63)==0){ rr1[t>>6]=s1; rr2[t>>6]=s2; }
  }
  __syncthreads();
  if (t < 128){
    float S1 = rr1[0]+rr1[1], S2 = rr2[0]+rr2[1];
    float mu = S1*(1.f/128.f);
    float var = S2*(1.f/128.f) - mu*mu;
    out[g*CC + t] = (y - mu) * rsqrtf(var + 1e-5f);
  }
}

extern "C" void kernel_launch(void* const* d_in, const int* in_sizes, int n_in,
                              void* d_out, int out_size, void* d_ws, size_t ws_size,
                              hipStream_t stream){
  const float* x     = (const float*)d_in[0];
  const int*   src   = (const int*)d_in[1];
  const int*   dst   = (const int*)d_in[2];
  const int*   gid   = (const int*)d_in[3];
  const float* fc1w  = (const float*)d_in[4];
  const float* al1   = (const float*)d_in[5];
  const float* ar1   = (const float*)d_in[6];
  const float* res1w = (const float*)d_in[7];
  const float* b1    = (const float*)d_in[8];
  const float* fc2w  = (const float*)d_in[9];
  const float* al2   = (const float*)d_in[10];
  const float* ar2   = (const float*)d_in[11];
  const float* b2    = (const float*)d_in[12];
  const float* aww   = (const float*)d_in[13];
  const float* awb   = (const float*)d_in[14];
  const float* outw  = (const float*)d_in[15];
  const float* outb  = (const float*)d_in[16];
  float* out = (float*)d_out;

  char* w = (char*)d_ws;
  unsigned short* featb = (unsigned short*)w;  w += (size_t)NN*CC*2;   // 25.6MB
  unsigned short* hb    = (unsigned short*)w;  w += (size_t)NN*CC*2;   // 25.6MB
  unsigned short* resb  = (unsigned short*)w;  w += (size_t)NN*CC*2;   // 25.6MB
  float*          el    = (float*)w;           w += (size_t)NN*HH*4;
  float*          er    = (float*)w;           w += (size_t)NN*HH*4;
  int*            deg   = (int*)w;             w += (size_t)NN*4;
  int*            rowptr= (int*)w;             w += (size_t)(NN+1)*4;
  int*            cursor= (int*)w;             w += (size_t)NN*4;
  int*            bsum  = (int*)w;             w += 128*4;
  int*            csr   = (int*)w;             w += (size_t)EE*4;
  int*            gptr  = (int*)w;             w += (size_t)(GG+1)*4;
  unsigned short* wb2   = (unsigned short*)w;  w += (size_t)CC*CC*2;
  unsigned short* xb    = (unsigned short*)w;  w += (size_t)NN*32*2;   // 6.4MB
  unsigned short* wb1   = (unsigned short*)w;  w += (size_t)CC*32*2;
  unsigned short* wrb   = (unsigned short*)w;  w += (size_t)CC*32*2;

  const int EB = (EE + 255)/256;

  // fused prep (deg zero, gptr, bf16 converts) + CSR build
  k_prep<<<(NN*32+255)/256,256,0,stream>>>(x, fc1w, res1w, fc2w, gid,
                                           xb, wb1, wrb, wb2, deg, gptr);
  k_count<<<EB,256,0,stream>>>(dst, deg);
  k_scan_local<<<NB,256,0,stream>>>(deg, rowptr, bsum);
  k_scan_bsums<<<1,64,0,stream>>>(bsum, rowptr);
  k_scan_add<<<NB,256,0,stream>>>(rowptr, bsum, cursor);
  k_scatter<<<EB,256,0,stream>>>(src, dst, cursor, csr);

  // layer 1 (MFMA)
  k_feat1m<<<1024,256,0,stream>>>(xb, wb1, wrb, b1, al1, ar1, featb, resb, el, er);
  k_aggr1<<<(NN+15)/16,256,0,stream>>>(rowptr, csr, el, er, featb, resb, hb);
  // layer 2
  k_feat2<<<(NN/16*2+3)/4,256,0,stream>>>(hb, wb2, al2, ar2, featb, el, er);
  // fused aggregation + readout + gnn_last + LayerNorm (block per graph)
  k_aggr2<<<GG,256,0,stream>>>(gptr, rowptr, csr, el, er, featb, hb,
                               b2, aww, awb, outw, outb, out);
}